// Round 2
// baseline (5803.351 us; speedup 1.0000x reference)
//
#include <hip/hip_runtime.h>
#include <math.h>

#define BB 64
#define LL 2048
#define CC 128
#define HH 128
#define KK 64
#define PP 336
#define EPSf 1e-5f

// ---------------------------------------------------------------------------
// RevIN column stats over L for [B, L, 128]: mean/rstd/std per (b, c)
// grid: B, block: (128, 8)
// ---------------------------------------------------------------------------
__global__ void colstats_kernel(const float* __restrict__ x, float* __restrict__ mean,
                                float* __restrict__ rstd, float* __restrict__ stdv) {
    int b = blockIdx.x;
    int c = threadIdx.x;
    int j = threadIdx.y;
    const float* xb = x + (size_t)b * LL * CC;
    float s = 0.f, s2 = 0.f;
    for (int l = j; l < LL; l += 8) {
        float v = xb[(size_t)l * CC + c];
        s += v; s2 += v * v;
    }
    __shared__ float shs[8][128];
    __shared__ float shq[8][128];
    shs[j][c] = s; shq[j][c] = s2;
    __syncthreads();
    if (j == 0) {
        float ts = 0.f, tq = 0.f;
        for (int i = 0; i < 8; ++i) { ts += shs[i][c]; tq += shq[i][c]; }
        float mu = ts * (1.f / LL);
        float var = tq * (1.f / LL) - mu * mu;
        var = fmaxf(var, 0.f);
        float sd = sqrtf(var + EPSf);
        mean[b * CC + c] = mu;
        stdv[b * CC + c] = sd;
        rstd[b * CC + c] = 1.f / sd;
    }
}

// ---------------------------------------------------------------------------
// General tiled f32 GEMM: Out = EP( ACT( NORM(A) @ W + bias ) )
// BM=BN=128, BK=32, 256 threads, 8x8 per thread.
// NORM: 0 none; 1 a'=(a-mu[off+k])*s[off+k] (RevIN, off=(m0/L)*normStride);
//       2 a'=(a-mu[k])*s[k]+t[k]  (feature BN affine)
// ACT: 0 none, 1 relu, 2 exact gelu
// EP:  0 plain; 1 Out[m,n] = v + Out[m,n] (residual in-place);
//      2 head: Out[(b*P+n)*C+c] = v*epS[m]+epM[m], m=b*C+c;
//      3 transposed residual: Out[(b*L+n)*C+c] += v, m=b*C+c
// ---------------------------------------------------------------------------
template <int NORM, int ACT, int EP>
__global__ __launch_bounds__(256)
void gemm_kernel(const float* __restrict__ A, const float* __restrict__ W,
                 const float* __restrict__ bias, float* __restrict__ Out,
                 int M, int N, int Kd, int lda, int ldw, int ldo,
                 const float* __restrict__ nmu, const float* __restrict__ ns,
                 const float* __restrict__ nt, int normStride,
                 const float* __restrict__ epS, const float* __restrict__ epM) {
    __shared__ float As[32][128];
    __shared__ float Ws[32][128];
    int tid = threadIdx.x;
    int tx = tid & 15, ty = tid >> 4;
    int n0 = blockIdx.x * 128;
    int m0 = blockIdx.y * 128;
    int noff = 0;
    if (NORM == 1) noff = (m0 / LL) * normStride;
    float acc[8][8] = {};

    for (int kt = 0; kt < Kd; kt += 32) {
        __syncthreads();
        // A tile -> As[k][m] (transposed)
        #pragma unroll
        for (int it = 0; it < 4; ++it) {
            int q = tid + it * 256;
            int row = q >> 3;
            int kq = (q & 7) << 2;
            float4 v = make_float4(0.f, 0.f, 0.f, 0.f);
            int m = m0 + row;
            if (m < M) v = *(const float4*)(A + (size_t)m * lda + kt + kq);
            if (NORM >= 1) {
                int kg = kt + kq;
                v.x = (v.x - nmu[noff + kg    ]) * ns[noff + kg    ];
                v.y = (v.y - nmu[noff + kg + 1]) * ns[noff + kg + 1];
                v.z = (v.z - nmu[noff + kg + 2]) * ns[noff + kg + 2];
                v.w = (v.w - nmu[noff + kg + 3]) * ns[noff + kg + 3];
                if (NORM == 2) {
                    v.x += nt[kg]; v.y += nt[kg + 1]; v.z += nt[kg + 2]; v.w += nt[kg + 3];
                }
            }
            As[kq    ][row] = v.x;
            As[kq + 1][row] = v.y;
            As[kq + 2][row] = v.z;
            As[kq + 3][row] = v.w;
        }
        // W tile -> Ws[k][n]
        #pragma unroll
        for (int it = 0; it < 4; ++it) {
            int q = tid + it * 256;
            int kr = q >> 5;
            int nc = (q & 31) << 2;
            int n = n0 + nc;
            float4 v = make_float4(0.f, 0.f, 0.f, 0.f);
            if (n < N) v = *(const float4*)(W + (size_t)(kt + kr) * ldw + n);
            *(float4*)&Ws[kr][nc] = v;
        }
        __syncthreads();
        #pragma unroll
        for (int k = 0; k < 32; ++k) {
            float a[8], w[8];
            *(float4*)&a[0] = *(const float4*)&As[k][ty * 8];
            *(float4*)&a[4] = *(const float4*)&As[k][ty * 8 + 4];
            *(float4*)&w[0] = *(const float4*)&Ws[k][tx * 4];
            *(float4*)&w[4] = *(const float4*)&Ws[k][64 + tx * 4];
            #pragma unroll
            for (int i = 0; i < 8; ++i)
                #pragma unroll
                for (int j = 0; j < 8; ++j)
                    acc[i][j] = fmaf(a[i], w[j], acc[i][j]);
        }
    }

    #pragma unroll
    for (int i = 0; i < 8; ++i) {
        int m = m0 + ty * 8 + i;
        if (m >= M) continue;
        #pragma unroll
        for (int jj = 0; jj < 8; jj += 4) {
            int n = n0 + (jj ? 64 + tx * 4 : tx * 4);
            if (n >= N) continue;
            float o[4];
            #pragma unroll
            for (int j = 0; j < 4; ++j) {
                float v = acc[i][jj + j] + (bias ? bias[n + j] : 0.f);
                if (ACT == 1) v = fmaxf(v, 0.f);
                if (ACT == 2) v = 0.5f * v * (1.f + erff(v * 0.70710678118654752f));
                o[j] = v;
            }
            if (EP == 0) {
                *(float4*)(Out + (size_t)m * ldo + n) = *(float4*)o;
            } else if (EP == 1) {
                float4 r = *(const float4*)(Out + (size_t)m * ldo + n);
                o[0] += r.x; o[1] += r.y; o[2] += r.z; o[3] += r.w;
                *(float4*)(Out + (size_t)m * ldo + n) = *(float4*)o;
            } else if (EP == 2) {
                int bb = m >> 7, cc = m & 127;
                float sc = epS[m], mn = epM[m];
                #pragma unroll
                for (int j = 0; j < 4; ++j)
                    Out[((size_t)bb * PP + (n + j)) * CC + cc] = o[j] * sc + mn;
            } else {  // EP == 3
                int bb = m >> 7, cc = m & 127;
                #pragma unroll
                for (int j = 0; j < 4; ++j) {
                    size_t idx = ((size_t)bb * LL + (n + j)) * CC + cc;
                    Out[idx] += o[j];
                }
            }
        }
    }
}

// ---------------------------------------------------------------------------
// normalize cluster embeds rows, write transposed cnT[h][k]
// ---------------------------------------------------------------------------
__global__ void cn_norm_kernel(const float* __restrict__ ce, float* __restrict__ cnT) {
    int k = blockIdx.x, h = threadIdx.x;
    float v = ce[(size_t)k * HH + h];
    __shared__ float sh[128];
    sh[h] = v * v;
    __syncthreads();
    for (int o = 64; o >= 1; o >>= 1) {
        if (h < o) sh[h] += sh[h + o];
        __syncthreads();
    }
    float nrm = sqrtf(sh[0]) + 1e-8f;
    cnT[(size_t)h * KK + k] = v / nrm;
}

// per-token 1/(||h||+1e-8)
__global__ void rownorm_kernel(const float* __restrict__ h, float* __restrict__ rn) {
    size_t row = (size_t)blockIdx.x * 256 + threadIdx.x;
    const float4* hp = (const float4*)(h + row * HH);
    float s = 0.f;
    #pragma unroll
    for (int i = 0; i < 32; ++i) {
        float4 v = hp[i];
        s += v.x * v.x + v.y * v.y + v.z * v.z + v.w * v.w;
    }
    rn[row] = 1.f / (sqrtf(s) + 1e-8f);
}

// Qp[k,h'] = (sum_h wk_w[h',h] * Q[k,h]) / sqrt(H);  qb[k] = (Q[k]. wk_b)/sqrt(H)
// grid K, block 128
__global__ void qprime_kernel(const float* __restrict__ Q, const float* __restrict__ wk_w,
                              const float* __restrict__ wk_b, float* __restrict__ Qp,
                              float* __restrict__ qb) {
    int k = blockIdx.x;
    int hp = threadIdx.x;
    __shared__ float qrow[128];
    __shared__ float red[128];
    qrow[hp] = Q[(size_t)k * HH + hp];
    __syncthreads();
    float s = 0.f;
    for (int h = 0; h < HH; ++h) s = fmaf(qrow[h], wk_w[(size_t)hp * HH + h], s);
    const float rs = 0.088388347648318447f;  // 1/sqrt(128)
    Qp[(size_t)k * HH + hp] = s * rs;
    red[hp] = qrow[hp] * wk_b[hp];
    __syncthreads();
    for (int o = 64; o >= 1; o >>= 1) {
        if (hp < o) red[hp] += red[hp + o];
        __syncthreads();
    }
    if (hp == 0) qb[k] = red[0] * rs;
}

// ---------------------------------------------------------------------------
// softmax over K=64, Bernoulli mask (uint8, transposed [B,K,L]), p-mean partials
// grid (L/32, B), block 256 (4 waves x 8 tokens)
// ---------------------------------------------------------------------------
__global__ __launch_bounds__(256)
void pmask_kernel(const float* __restrict__ sp, const float* __restrict__ rn,
                  const float* __restrict__ bern, unsigned char* __restrict__ Mt,
                  float* __restrict__ ppart) {
    int b = blockIdx.y;
    int l0 = blockIdx.x * 32;
    int tid = threadIdx.x;
    int wv = tid >> 6, lane = tid & 63;
    __shared__ float Msh[64][33];
    __shared__ float psum[4][64];
    float pa = 0.f;
    for (int tt = 0; tt < 8; ++tt) {
        int l = l0 + wv * 8 + tt;
        size_t tok = (size_t)b * LL + l;
        float s = sp[tok * 64 + lane] * rn[tok];
        float mx = s;
        #pragma unroll
        for (int o = 32; o >= 1; o >>= 1) mx = fmaxf(mx, __shfl_xor(mx, o));
        float ev = expf(s - mx);
        float sm = ev;
        #pragma unroll
        for (int o = 32; o >= 1; o >>= 1) sm += __shfl_xor(sm, o);
        float p = ev / sm;
        pa += p;
        Msh[lane][wv * 8 + tt] = (bern[tok * KK + lane] < p) ? 1.f : 0.f;
    }
    psum[wv][lane] = pa;
    __syncthreads();
    for (int q = tid; q < 64 * 32; q += 256) {
        int k = q >> 5, j = q & 31;
        Mt[((size_t)b * KK + k) * LL + l0 + j] = (unsigned char)Msh[k][j];
    }
    if (tid < 64)
        ppart[((size_t)b * (LL / 32) + blockIdx.x) * KK + tid] =
            psum[0][tid] + psum[1][tid] + psum[2][tid] + psum[3][tid];
}

__global__ void pmean_final_kernel(const float* __restrict__ part, float* __restrict__ pm) {
    int b = blockIdx.x, k = threadIdx.x;   // block 64
    float s = 0.f;
    for (int i = 0; i < LL / 32; ++i) s += part[((size_t)b * (LL / 32) + i) * KK + k];
    pm[b * KK + k] = s * (1.f / LL);
}

// ---------------------------------------------------------------------------
// scores[b,k,l] = Qp[k,:].h[b,l,:] + qb[k];  grid (L/128, B), block 256
// ---------------------------------------------------------------------------
__global__ __launch_bounds__(256)
void scores_kernel(const float* __restrict__ Qp, const float* __restrict__ hmat,
                   const float* __restrict__ qb, float* __restrict__ S) {
    __shared__ float QT[128][64];   // [h][k]
    __shared__ float KT[32][128];   // [h][l]
    int tid = threadIdx.x;
    int b = blockIdx.y;
    int l0 = blockIdx.x * 128;
    for (int q = tid; q < 64 * 128; q += 256) {
        int k = q >> 7, h = q & 127;
        QT[h][k] = Qp[q];
    }
    int tx = tid & 15, ty = tid >> 4;
    float acc[4][8] = {};
    const float* Kb = hmat + (size_t)b * LL * HH;
    for (int ht = 0; ht < HH; ht += 32) {
        __syncthreads();
        #pragma unroll
        for (int it = 0; it < 4; ++it) {
            int q = tid + it * 256;
            int row = q >> 3;
            int hq = (q & 7) << 2;
            float4 v = *(const float4*)(Kb + (size_t)(l0 + row) * HH + ht + hq);
            KT[hq][row] = v.x; KT[hq + 1][row] = v.y;
            KT[hq + 2][row] = v.z; KT[hq + 3][row] = v.w;
        }
        __syncthreads();
        #pragma unroll
        for (int h = 0; h < 32; ++h) {
            float qv[4], kv[8];
            *(float4*)&qv[0] = *(const float4*)&QT[ht + h][ty * 4];
            *(float4*)&kv[0] = *(const float4*)&KT[h][tx * 4];
            *(float4*)&kv[4] = *(const float4*)&KT[h][64 + tx * 4];
            #pragma unroll
            for (int i = 0; i < 4; ++i)
                #pragma unroll
                for (int j = 0; j < 8; ++j)
                    acc[i][j] = fmaf(qv[i], kv[j], acc[i][j]);
        }
    }
    #pragma unroll
    for (int i = 0; i < 4; ++i) {
        int k = ty * 4 + i;
        float bq = qb[k];
        #pragma unroll
        for (int jj = 0; jj < 8; jj += 4) {
            int l = l0 + (jj ? 64 + tx * 4 : tx * 4);
            float o[4];
            #pragma unroll
            for (int j = 0; j < 4; ++j) o[j] = acc[i][jj + j] + bq;
            *(float4*)(S + ((size_t)b * KK + k) * LL + l) = *(float4*)o;
        }
    }
}

// ---------------------------------------------------------------------------
// aw = softmax_l( exp(scores) * Mt ), in place on S.  grid B*K, block 256
// ---------------------------------------------------------------------------
__global__ __launch_bounds__(256)
void aw_kernel(float* __restrict__ S, const unsigned char* __restrict__ Mt) {
    size_t base = (size_t)blockIdx.x * LL;
    int tid = threadIdx.x;
    float t[8];
    float mx = -1e30f;
    #pragma unroll
    for (int i = 0; i < 8; ++i) {
        int l = tid + i * 256;
        float v = expf(S[base + l]) * (float)Mt[base + l];
        t[i] = v;
        mx = fmaxf(mx, v);
    }
    __shared__ float shA[4];
    __shared__ float shB[4];
    #pragma unroll
    for (int o = 32; o >= 1; o >>= 1) mx = fmaxf(mx, __shfl_xor(mx, o));
    if ((tid & 63) == 0) shA[tid >> 6] = mx;
    __syncthreads();
    mx = fmaxf(fmaxf(shA[0], shA[1]), fmaxf(shA[2], shA[3]));
    float e[8];
    float sum = 0.f;
    #pragma unroll
    for (int i = 0; i < 8; ++i) { e[i] = expf(t[i] - mx); sum += e[i]; }
    #pragma unroll
    for (int o = 32; o >= 1; o >>= 1) sum += __shfl_xor(sum, o);
    if ((tid & 63) == 0) shB[tid >> 6] = sum;
    __syncthreads();
    sum = (shB[0] + shB[1]) + (shB[2] + shB[3]);
    float inv = 1.f / sum;
    #pragma unroll
    for (int i = 0; i < 8; ++i) S[base + tid + i * 256] = e[i] * inv;
}

// ---------------------------------------------------------------------------
// awh split-L partials: part[b,sp,k,h] = sum_{l in 512-chunk} aw[b,k,l]*h[b,l,h]
// grid (4, B), block 256
// ---------------------------------------------------------------------------
__global__ __launch_bounds__(256)
void awh_part_kernel(const float* __restrict__ AWs, const float* __restrict__ hmat,
                     float* __restrict__ part) {
    __shared__ float AT[32][64];    // [l][k]
    __shared__ float VT[32][128];   // [l][h]
    int b = blockIdx.y, sp = blockIdx.x;
    int tid = threadIdx.x;
    int tx = tid & 15, ty = tid >> 4;
    float acc[4][8] = {};
    const float* Ab = AWs + (size_t)b * KK * LL + sp * 512;
    const float* Vb = hmat + ((size_t)b * LL + sp * 512) * HH;
    for (int lt = 0; lt < 512; lt += 32) {
        __syncthreads();
        #pragma unroll
        for (int it = 0; it < 2; ++it) {
            int q = tid + it * 256;
            int row = q >> 3;          // k 0..63
            int lq = (q & 7) << 2;
            float4 v = *(const float4*)(Ab + (size_t)row * LL + lt + lq);
            AT[lq][row] = v.x; AT[lq + 1][row] = v.y;
            AT[lq + 2][row] = v.z; AT[lq + 3][row] = v.w;
        }
        #pragma unroll
        for (int it = 0; it < 4; ++it) {
            int q = tid + it * 256;
            int lr = q >> 5;
            int hc = (q & 31) << 2;
            *(float4*)&VT[lr][hc] = *(const float4*)(Vb + (size_t)(lt + lr) * HH + hc);
        }
        __syncthreads();
        #pragma unroll
        for (int l = 0; l < 32; ++l) {
            float av[4], vv[8];
            *(float4*)&av[0] = *(const float4*)&AT[l][ty * 4];
            *(float4*)&vv[0] = *(const float4*)&VT[l][tx * 4];
            *(float4*)&vv[4] = *(const float4*)&VT[l][64 + tx * 4];
            #pragma unroll
            for (int i = 0; i < 4; ++i)
                #pragma unroll
                for (int j = 0; j < 8; ++j)
                    acc[i][j] = fmaf(av[i], vv[j], acc[i][j]);
        }
    }
    #pragma unroll
    for (int i = 0; i < 4; ++i) {
        int k = ty * 4 + i;
        #pragma unroll
        for (int jj = 0; jj < 8; jj += 4) {
            int h = (jj ? 64 + tx * 4 : tx * 4);
            float o[4];
            #pragma unroll
            for (int j = 0; j < 4; ++j) o[j] = acc[i][jj + j];
            *(float4*)(part + (((size_t)b * 4 + sp) * KK + k) * HH + h) = *(float4*)o;
        }
    }
}

// awh[b,k,h] = sum_sp part[b,sp,k,h];  grid B*K, block 128
__global__ void awh_reduce_kernel(const float* __restrict__ part, float* __restrict__ awh) {
    int bk = blockIdx.x, h = threadIdx.x;
    int b = bk >> 6, k = bk & 63;
    float s = 0.f;
    #pragma unroll
    for (int sp = 0; sp < 4; ++sp)
        s += part[(((size_t)b * 4 + sp) * KK + k) * HH + h];
    awh[(size_t)bk * HH + h] = s;
}

// new_cluster_embeds[k,h] = mean_b( ao[b,k,h] * pmean[b,k] )
__global__ void newce_kernel(const float* __restrict__ ao, const float* __restrict__ pm,
                             float* __restrict__ outTail) {
    int k = blockIdx.x, h = threadIdx.x;   // block 128
    float s = 0.f;
    for (int b = 0; b < BB; ++b)
        s += ao[((size_t)b * KK + k) * HH + h] * pm[b * KK + k];
    outTail[(size_t)k * HH + h] = s * (1.f / BB);
}

// z = (h2 - mean2) * rstd2, elementwise in-place
__global__ void revin_apply_kernel(float* __restrict__ z,
                                   const float* __restrict__ mu, const float* __restrict__ rs) {
    size_t total = (size_t)BB * LL * CC;
    for (size_t i = (size_t)blockIdx.x * 256 + threadIdx.x; i < total;
         i += (size_t)gridDim.x * 256) {
        size_t b = i / ((size_t)LL * CC);
        int c = (int)(i & 127);
        z[i] = (z[i] - mu[b * CC + c]) * rs[b * CC + c];
    }
}

// timestep BN stats: per l over (b, c).  grid L, block 256
__global__ __launch_bounds__(256)
void bnt_stats_kernel(const float* __restrict__ z, float* __restrict__ mu,
                      float* __restrict__ rv) {
    int l = blockIdx.x;
    int tid = threadIdx.x;
    float s = 0.f, s2 = 0.f;
    for (int i = tid; i < BB * CC; i += 256) {
        int b = i >> 7, c = i & 127;
        float v = z[((size_t)b * LL + l) * CC + c];
        s += v; s2 += v * v;
    }
    #pragma unroll
    for (int o = 32; o >= 1; o >>= 1) { s += __shfl_xor(s, o); s2 += __shfl_xor(s2, o); }
    __shared__ float shA[4];
    __shared__ float shB[4];
    if ((tid & 63) == 0) { shA[tid >> 6] = s; shB[tid >> 6] = s2; }
    __syncthreads();
    if (tid == 0) {
        float ts = (shA[0] + shA[1]) + (shA[2] + shA[3]);
        float tq = (shB[0] + shB[1]) + (shB[2] + shB[3]);
        float m = ts / (float)(BB * CC);
        float var = tq / (float)(BB * CC) - m * m;
        var = fmaxf(var, 0.f);
        mu[l] = m;
        rv[l] = 1.f / sqrtf(var + EPSf);
    }
}

// [B,L,C] -> [B,C,L], optional timestep-BN applied on the fly
template <bool DO_BN>
__global__ void transpose_bn_kernel(const float* __restrict__ in, float* __restrict__ out,
                                    const float* __restrict__ mu, const float* __restrict__ rv,
                                    const float* __restrict__ g, const float* __restrict__ be) {
    __shared__ float tile[32][33];
    int l0 = blockIdx.x * 32, c0 = blockIdx.y * 32, b = blockIdx.z;
    int tx = threadIdx.x, ty = threadIdx.y;
    const float* ib = in + (size_t)b * LL * CC;
    for (int i = ty; i < 32; i += 8) {
        int l = l0 + i;
        float v = ib[(size_t)l * CC + c0 + tx];
        if (DO_BN) v = (v - mu[l]) * rv[l] * g[l] + be[l];
        tile[i][tx] = v;
    }
    __syncthreads();
    float* ob = out + (size_t)b * CC * LL;
    for (int i = ty; i < 32; i += 8)
        ob[(size_t)(c0 + i) * LL + l0 + tx] = tile[tx][i];
}

// feature BN partial stats: grid 1024, block 128 (c)
__global__ void bnf_part_kernel(const float* __restrict__ z, float* __restrict__ part) {
    int c = threadIdx.x;
    const int rows = (BB * LL) / 1024;   // 128
    size_t r0 = (size_t)blockIdx.x * rows;
    float s = 0.f, s2 = 0.f;
    for (int r = 0; r < rows; ++r) {
        float v = z[(r0 + r) * CC + c];
        s += v; s2 += v * v;
    }
    part[(size_t)blockIdx.x * 256 + c] = s;
    part[(size_t)blockIdx.x * 256 + 128 + c] = s2;
}

__global__ void bnf_final_kernel(const float* __restrict__ part, const float* __restrict__ g,
                                 const float* __restrict__ be, float* __restrict__ mu,
                                 float* __restrict__ sA, float* __restrict__ tA) {
    int c = threadIdx.x;   // block 128
    float s = 0.f, s2 = 0.f;
    for (int i = 0; i < 1024; ++i) {
        s += part[(size_t)i * 256 + c];
        s2 += part[(size_t)i * 256 + 128 + c];
    }
    float m = s / (float)(BB * LL);
    float var = s2 / (float)(BB * LL) - m * m;
    var = fmaxf(var, 0.f);
    float rvv = 1.f / sqrtf(var + EPSf);
    mu[c] = m;
    sA[c] = rvv * g[c];
    tA[c] = be[c];
}

// ---------------------------------------------------------------------------
extern "C" void kernel_launch(void* const* d_in, const int* in_sizes, int n_in,
                              void* d_out, int out_size, void* d_ws, size_t ws_size,
                              hipStream_t stream) {
    const float* x     = (const float*)d_in[0];
    const float* bern  = (const float*)d_in[1];
    const float* ce    = (const float*)d_in[2];
    const float* wq_w  = (const float*)d_in[3];
    const float* wq_b  = (const float*)d_in[4];
    const float* wk_w  = (const float*)d_in[5];
    const float* wk_b  = (const float*)d_in[6];
    const float* wv_w  = (const float*)d_in[7];
    const float* wv_b  = (const float*)d_in[8];
    const float* cm_w1 = (const float*)d_in[9];
    const float* cm_b1 = (const float*)d_in[10];
    const float* cm_w2 = (const float*)d_in[11];
    const float* cm_b2 = (const float*)d_in[12];
    const float* tm_w1 = (const float*)d_in[13];
    const float* tm_b1 = (const float*)d_in[14];
    const float* tm_w2 = (const float*)d_in[15];
    const float* tm_b2 = (const float*)d_in[16];
    const float* bn_t_g = (const float*)d_in[17];
    const float* bn_t_b = (const float*)d_in[18];
    const float* lin_t_w = (const float*)d_in[19];
    const float* lin_t_b = (const float*)d_in[20];
    const float* bn_f_g = (const float*)d_in[21];
    const float* bn_f_b = (const float*)d_in[22];
    const float* f1_w  = (const float*)d_in[23];
    const float* f1_b  = (const float*)d_in[24];
    const float* f2_w  = (const float*)d_in[25];
    const float* f2_b  = (const float*)d_in[26];
    const float* out_w = (const float*)d_in[27];
    const float* out_b = (const float*)d_in[28];
    (void)in_sizes; (void)n_in; (void)out_size;

    float* y = (float*)d_out;                         // [B,P,C]
    float* ceOut = y + (size_t)BB * PP * CC;          // [K,H]

    // workspace carve-up (~183 MB)
    float* ws = (float*)d_ws;
    size_t off = 0;
    auto alloc = [&](size_t n) { float* p = ws + off; off += n; return p; };
    float* mean1  = alloc(BB * CC);
    float* rstd1  = alloc(BB * CC);
    float* std1   = alloc(BB * CC);
    float* mean2  = alloc(BB * CC);
    float* rstd2  = alloc(BB * CC);
    float* std2   = alloc(BB * CC);
    float* bnmu   = alloc(LL);
    float* bnrv   = alloc(LL);
    float* bfpart = alloc(1024 * 256);
    float* bfmu   = alloc(CC);
    float* bfs    = alloc(CC);
    float* bft    = alloc(CC);
    float* qbuf   = alloc(KK * HH);
    float* qp     = alloc(KK * HH);
    float* qb     = alloc(KK);
    float* cnT    = alloc(HH * KK);
    float* rn     = alloc((size_t)BB * LL);
    float* ppart  = alloc((size_t)BB * (LL / 32) * KK);
    float* pmean  = alloc(BB * KK);
    float* awhprt = alloc((size_t)BB * 4 * KK * HH);
    float* awh    = alloc((size_t)BB * KK * HH);
    float* aobuf  = alloc((size_t)BB * KK * HH);
    float* S      = alloc((size_t)BB * KK * LL);
    float* buf0   = alloc((size_t)BB * LL * CC);
    float* buf2   = alloc((size_t)BB * LL * CC);
    unsigned char* Mt = (unsigned char*)(ws + off);   // [B,K,L] u8, 8 MB
    (void)ws_size;

    const int ML = BB * LL;      // 131072
    dim3 g1024(1, ML / 128);
    dim3 tb(32, 8);
    dim3 tgrid(LL / 32, CC / 32, BB);

    // 1) RevIN-1 stats on x
    colstats_kernel<<<dim3(BB), dim3(128, 8), 0, stream>>>(x, mean1, rstd1, std1);
    // 2) buf0 = relu(norm(x) @ cm_w1 + cm_b1)
    gemm_kernel<1, 1, 0><<<g1024, 256, 0, stream>>>(x, cm_w1, cm_b1, buf0,
        ML, HH, CC, CC, HH, HH, mean1, rstd1, nullptr, CC, nullptr, nullptr);
    // 3) h = buf2 = buf0 @ cm_w2 + cm_b2
    gemm_kernel<0, 0, 0><<<g1024, 256, 0, stream>>>(buf0, cm_w2, cm_b2, buf2,
        ML, HH, HH, HH, HH, HH, nullptr, nullptr, nullptr, 0, nullptr, nullptr);
    // 4) Q = ce @ wq_w + wq_b; then Qp = Q @ wk_w^T / sqrt(H), qb = Q.wk_b / sqrt(H)
    gemm_kernel<0, 0, 0><<<dim3(1, 1), 256, 0, stream>>>(ce, wq_w, wq_b, qbuf,
        KK, HH, HH, HH, HH, HH, nullptr, nullptr, nullptr, 0, nullptr, nullptr);
    qprime_kernel<<<dim3(KK), dim3(128), 0, stream>>>(qbuf, wk_w, wk_b, qp, qb);
    // 5) normalized codebook (transposed)
    cn_norm_kernel<<<dim3(KK), dim3(128), 0, stream>>>(ce, cnT);
    // 6) per-token 1/(||h||+1e-8)
    rownorm_kernel<<<dim3(ML / 256), 256, 0, stream>>>(buf2, rn);
    // 7) raw routing scores: S[B*L,64] = h @ cnT
    gemm_kernel<0, 0, 0><<<g1024, 256, 0, stream>>>(buf2, cnT, nullptr, S,
        ML, KK, HH, HH, KK, KK, nullptr, nullptr, nullptr, 0, nullptr, nullptr);
    // 8) softmax/bernoulli-mask/p-mean
    pmask_kernel<<<dim3(LL / 32, BB), 256, 0, stream>>>(S, rn, bern, Mt, ppart);
    pmean_final_kernel<<<dim3(BB), dim3(64), 0, stream>>>(ppart, pmean);
    // 9) attention scores (overwrites S as [B,K,L]) directly from h
    scores_kernel<<<dim3(LL / 128, BB), 256, 0, stream>>>(qp, buf2, qb, S);
    // 10) masked double-exp softmax over L
    aw_kernel<<<dim3(BB * KK), 256, 0, stream>>>(S, Mt);
    // 11) awh = aw @ h (split-L), then ao = awh @ wv_w + wv_b, then cluster update
    awh_part_kernel<<<dim3(4, BB), 256, 0, stream>>>(S, buf2, awhprt);
    awh_reduce_kernel<<<dim3(BB * KK), dim3(128), 0, stream>>>(awhprt, awh);
    gemm_kernel<0, 0, 0><<<dim3(1, (BB * KK) / 128), 256, 0, stream>>>(awh, wv_w, wv_b, aobuf,
        BB * KK, HH, HH, HH, HH, HH, nullptr, nullptr, nullptr, 0, nullptr, nullptr);
    newce_kernel<<<dim3(KK), dim3(128), 0, stream>>>(aobuf, pmean, ceOut);
    // 12) temporal module: h2 = relu(h@tm_w1+b)@tm_w2+b  (h dead after first GEMM)
    gemm_kernel<0, 1, 0><<<g1024, 256, 0, stream>>>(buf2, tm_w1, tm_b1, buf0,
        ML, HH, HH, HH, HH, HH, nullptr, nullptr, nullptr, 0, nullptr, nullptr);
    gemm_kernel<0, 0, 0><<<g1024, 256, 0, stream>>>(buf0, tm_w2, tm_b2, buf2,
        ML, HH, HH, HH, HH, HH, nullptr, nullptr, nullptr, 0, nullptr, nullptr);
    // 13) RevIN-2: stats + apply in place -> z in buf2
    colstats_kernel<<<dim3(BB), dim3(128, 8), 0, stream>>>(buf2, mean2, rstd2, std2);
    revin_apply_kernel<<<dim3(2048), 256, 0, stream>>>(buf2, mean2, rstd2);
    // 14) 4 mixer blocks (z stays in buf2; buf0 is the only temp)
    for (int blkI = 0; blkI < 4; ++blkI) {
        bnt_stats_kernel<<<dim3(LL), 256, 0, stream>>>(buf2, bnmu, bnrv);
        transpose_bn_kernel<true><<<tgrid, tb, 0, stream>>>(buf2, buf0, bnmu, bnrv, bn_t_g, bn_t_b);
        // timestep GEMM with transposed-residual epilogue into z
        gemm_kernel<0, 2, 3><<<dim3(LL / 128, (BB * CC) / 128), 256, 0, stream>>>(
            buf0, lin_t_w, lin_t_b, buf2,
            BB * CC, LL, LL, LL, LL, 0, nullptr, nullptr, nullptr, 0, nullptr, nullptr);
        bnf_part_kernel<<<dim3(1024), dim3(128), 0, stream>>>(buf2, bfpart);
        bnf_final_kernel<<<dim3(1), dim3(128), 0, stream>>>(bfpart, bn_f_g, bn_f_b, bfmu, bfs, bft);
        gemm_kernel<2, 2, 0><<<g1024, 256, 0, stream>>>(buf2, f1_w, f1_b, buf0,
            ML, HH, CC, CC, HH, HH, bfmu, bfs, bft, 0, nullptr, nullptr);
        gemm_kernel<0, 0, 1><<<g1024, 256, 0, stream>>>(buf0, f2_w, f2_b, buf2,
            ML, CC, HH, HH, CC, CC, nullptr, nullptr, nullptr, 0, nullptr, nullptr);
    }
    // 15) head: y[b,p,c] = (z^T @ out_w + out_b) * std2 + mean2
    transpose_bn_kernel<false><<<tgrid, tb, 0, stream>>>(buf2, buf0,
        nullptr, nullptr, nullptr, nullptr);
    gemm_kernel<0, 0, 2><<<dim3((PP + 127) / 128, (BB * CC) / 128), 256, 0, stream>>>(
        buf0, out_w, out_b, y,
        BB * CC, PP, LL, LL, PP, 0, nullptr, nullptr, nullptr, 0, std2, mean2);
}

// Round 3
// 2360.332 us; speedup vs baseline: 2.4587x; 2.4587x over previous
//
#include <hip/hip_runtime.h>
#include <math.h>

#define BB 64
#define LL 2048
#define CC 128
#define HH 128
#define KK 64
#define PP 336
#define EPSf 1e-5f

typedef __attribute__((ext_vector_type(8))) short short8v;
typedef __attribute__((ext_vector_type(4))) float float4v;

__device__ inline ushort f2bf(float f) {
    union { float f; unsigned u; } v; v.f = f;
    unsigned r = (v.u + 0x7FFFu + ((v.u >> 16) & 1u)) >> 16;
    return (ushort)r;
}

// ---------------------------------------------------------------------------
// RevIN column stats over L for [B, L, 128]: mean/rstd/std per (b, c)
// ---------------------------------------------------------------------------
__global__ void colstats_kernel(const float* __restrict__ x, float* __restrict__ mean,
                                float* __restrict__ rstd, float* __restrict__ stdv) {
    int b = blockIdx.x;
    int c = threadIdx.x;
    int j = threadIdx.y;
    const float* xb = x + (size_t)b * LL * CC;
    float s = 0.f, s2 = 0.f;
    for (int l = j; l < LL; l += 8) {
        float v = xb[(size_t)l * CC + c];
        s += v; s2 += v * v;
    }
    __shared__ float shs[8][128];
    __shared__ float shq[8][128];
    shs[j][c] = s; shq[j][c] = s2;
    __syncthreads();
    if (j == 0) {
        float ts = 0.f, tq = 0.f;
        for (int i = 0; i < 8; ++i) { ts += shs[i][c]; tq += shq[i][c]; }
        float mu = ts * (1.f / LL);
        float var = tq * (1.f / LL) - mu * mu;
        var = fmaxf(var, 0.f);
        float sd = sqrtf(var + EPSf);
        mean[b * CC + c] = mu;
        stdv[b * CC + c] = sd;
        rstd[b * CC + c] = 1.f / sd;
    }
}

// ---------------------------------------------------------------------------
// f32 VALU GEMM (kept for the K=128 shapes)
// ---------------------------------------------------------------------------
template <int NORM, int ACT, int EP>
__global__ __launch_bounds__(256)
void gemm_kernel(const float* __restrict__ A, const float* __restrict__ W,
                 const float* __restrict__ bias, float* __restrict__ Out,
                 int M, int N, int Kd, int lda, int ldw, int ldo,
                 const float* __restrict__ nmu, const float* __restrict__ ns,
                 const float* __restrict__ nt, int normStride) {
    __shared__ float As[32][128];
    __shared__ float Ws[32][128];
    int tid = threadIdx.x;
    int tx = tid & 15, ty = tid >> 4;
    int n0 = blockIdx.x * 128;
    int m0 = blockIdx.y * 128;
    int noff = 0;
    if (NORM == 1) noff = (m0 / LL) * normStride;
    float acc[8][8] = {};

    for (int kt = 0; kt < Kd; kt += 32) {
        __syncthreads();
        #pragma unroll
        for (int it = 0; it < 4; ++it) {
            int q = tid + it * 256;
            int row = q >> 3;
            int kq = (q & 7) << 2;
            float4 v = make_float4(0.f, 0.f, 0.f, 0.f);
            int m = m0 + row;
            if (m < M) v = *(const float4*)(A + (size_t)m * lda + kt + kq);
            if (NORM >= 1) {
                int kg = kt + kq;
                v.x = (v.x - nmu[noff + kg    ]) * ns[noff + kg    ];
                v.y = (v.y - nmu[noff + kg + 1]) * ns[noff + kg + 1];
                v.z = (v.z - nmu[noff + kg + 2]) * ns[noff + kg + 2];
                v.w = (v.w - nmu[noff + kg + 3]) * ns[noff + kg + 3];
                if (NORM == 2) {
                    v.x += nt[kg]; v.y += nt[kg + 1]; v.z += nt[kg + 2]; v.w += nt[kg + 3];
                }
            }
            As[kq    ][row] = v.x;
            As[kq + 1][row] = v.y;
            As[kq + 2][row] = v.z;
            As[kq + 3][row] = v.w;
        }
        #pragma unroll
        for (int it = 0; it < 4; ++it) {
            int q = tid + it * 256;
            int kr = q >> 5;
            int nc = (q & 31) << 2;
            int n = n0 + nc;
            float4 v = make_float4(0.f, 0.f, 0.f, 0.f);
            if (n < N) v = *(const float4*)(W + (size_t)(kt + kr) * ldw + n);
            *(float4*)&Ws[kr][nc] = v;
        }
        __syncthreads();
        #pragma unroll
        for (int k = 0; k < 32; ++k) {
            float a[8], w[8];
            *(float4*)&a[0] = *(const float4*)&As[k][ty * 8];
            *(float4*)&a[4] = *(const float4*)&As[k][ty * 8 + 4];
            *(float4*)&w[0] = *(const float4*)&Ws[k][tx * 4];
            *(float4*)&w[4] = *(const float4*)&Ws[k][64 + tx * 4];
            #pragma unroll
            for (int i = 0; i < 8; ++i)
                #pragma unroll
                for (int j = 0; j < 8; ++j)
                    acc[i][j] = fmaf(a[i], w[j], acc[i][j]);
        }
    }

    #pragma unroll
    for (int i = 0; i < 8; ++i) {
        int m = m0 + ty * 8 + i;
        if (m >= M) continue;
        #pragma unroll
        for (int jj = 0; jj < 8; jj += 4) {
            int n = n0 + (jj ? 64 + tx * 4 : tx * 4);
            if (n >= N) continue;
            float o[4];
            #pragma unroll
            for (int j = 0; j < 4; ++j) {
                float v = acc[i][jj + j] + (bias ? bias[n + j] : 0.f);
                if (ACT == 1) v = fmaxf(v, 0.f);
                if (ACT == 2) v = 0.5f * v * (1.f + erff(v * 0.70710678118654752f));
                o[j] = v;
            }
            if (EP == 0) {
                *(float4*)(Out + (size_t)m * ldo + n) = *(float4*)o;
            } else {  // EP == 1 residual in-place
                float4 r = *(const float4*)(Out + (size_t)m * ldo + n);
                o[0] += r.x; o[1] += r.y; o[2] += r.z; o[3] += r.w;
                *(float4*)(Out + (size_t)m * ldo + n) = *(float4*)o;
            }
        }
    }
}

// ---------------------------------------------------------------------------
// bf16 MFMA GEMM: A [M][K] bf16 (k-contig), W [N][K] bf16 (k-contig).
// 128x128 tile, BK=64, 4 waves, 16x16x32 MFMA, f32 accum.
// EPM=1: v=gelu(acc+bias[n]); Z[(b*LDO+n)*128+c] += v   (m = b*128+c)
// EPM=2: v=acc+bias[n];       Z[(b*LDO+n)*128+c] = v*epS[m]+epM[m]
// ---------------------------------------------------------------------------
template <int EPM>
__global__ __launch_bounds__(256)
void mfma_gemm_kernel(const ushort* __restrict__ A, const ushort* __restrict__ W,
                      const float* __restrict__ bias, float* Z,
                      int M, int N, int Kd, int LDO,
                      const float* __restrict__ epS, const float* __restrict__ epM) {
    __shared__ ushort Al[128][72];
    __shared__ ushort Bl[128][72];
    __shared__ float Ol[32][132];

    int tid = threadIdx.x;
    int w = tid >> 6, lane = tid & 63;
    int wm = (w >> 1) * 64, wn = (w & 1) * 64;
    int col = lane & 15, kq = lane >> 4;
    int n0 = blockIdx.x * 128;
    int m0 = blockIdx.y * 128;

    float4v acc[4][4];
    #pragma unroll
    for (int i = 0; i < 4; ++i)
        #pragma unroll
        for (int j = 0; j < 4; ++j) acc[i][j] = (float4v){0.f, 0.f, 0.f, 0.f};

    int kTiles = Kd >> 6;
    for (int kt = 0; kt < kTiles; ++kt) {
        __syncthreads();
        #pragma unroll
        for (int it = 0; it < 4; ++it) {
            int q = tid + it * 256;
            int row = q >> 3, part = q & 7;
            short8v v = *(const short8v*)(A + (size_t)(m0 + row) * Kd + (kt << 6) + part * 8);
            *(short8v*)&Al[row][part * 8] = v;
        }
        #pragma unroll
        for (int it = 0; it < 4; ++it) {
            int q = tid + it * 256;
            int row = q >> 3, part = q & 7;
            short8v v = {};
            if (EPM != 2 || n0 + row < N)
                v = *(const short8v*)(W + (size_t)(n0 + row) * Kd + (kt << 6) + part * 8);
            *(short8v*)&Bl[row][part * 8] = v;
        }
        __syncthreads();
        #pragma unroll
        for (int ksub = 0; ksub < 2; ++ksub) {
            short8v af[4], bf[4];
            #pragma unroll
            for (int mf = 0; mf < 4; ++mf)
                af[mf] = *(const short8v*)&Al[wm + mf * 16 + col][ksub * 32 + kq * 8];
            #pragma unroll
            for (int nf = 0; nf < 4; ++nf)
                bf[nf] = *(const short8v*)&Bl[wn + nf * 16 + col][ksub * 32 + kq * 8];
            #pragma unroll
            for (int mf = 0; mf < 4; ++mf)
                #pragma unroll
                for (int nf = 0; nf < 4; ++nf)
                    acc[mf][nf] = __builtin_amdgcn_mfma_f32_16x16x32_bf16(
                        af[mf], bf[nf], acc[mf][nf], 0, 0, 0);
        }
    }

    // Epilogue: 4 rounds of 32-n strips through Ol, then coalesced global phase.
    int b = m0 >> 7;
    #pragma unroll
    for (int q = 0; q < 4; ++q) {
        __syncthreads();
        #pragma unroll
        for (int nf = 0; nf < 4; ++nf) {
            int gnl = wn + nf * 16;
            if ((gnl >> 5) != q) continue;
            int gn = n0 + gnl + col;
            float bn = (EPM == 2 && gn >= N) ? 0.f : bias[gn];
            int nl = gnl - q * 32 + col;
            #pragma unroll
            for (int mf = 0; mf < 4; ++mf) {
                #pragma unroll
                for (int r = 0; r < 4; ++r) {
                    float v = acc[mf][nf][r] + bn;
                    if (EPM == 1) v = 0.5f * v * (1.f + erff(v * 0.70710678118654752f));
                    Ol[nl][wm + mf * 16 + kq * 4 + r] = v;
                }
            }
        }
        __syncthreads();
        int nloc = tid >> 3, c0 = (tid & 7) * 16;
        int gn = n0 + q * 32 + nloc;
        if (EPM == 2 && gn >= N) continue;
        float* zr = Z + ((size_t)b * LDO + gn) * CC + c0;
        #pragma unroll
        for (int i = 0; i < 4; ++i) {
            float4 v = *(float4*)&Ol[nloc][c0 + i * 4];
            if (EPM == 1) {
                float4 o = *(float4*)(zr + i * 4);
                v.x += o.x; v.y += o.y; v.z += o.z; v.w += o.w;
                *(float4*)(zr + i * 4) = v;
            } else {
                int mb = m0 + c0 + i * 4;
                float4 s4 = *(const float4*)(epS + mb);
                float4 m4 = *(const float4*)(epM + mb);
                v.x = v.x * s4.x + m4.x; v.y = v.y * s4.y + m4.y;
                v.z = v.z * s4.z + m4.z; v.w = v.w * s4.w + m4.w;
                *(float4*)(zr + i * 4) = v;
            }
        }
    }
}

// W [K][N] f32 -> WT [N][K] bf16  (block (32,8), grid (K/32, ceil(N/32)))
__global__ void wtrans_kernel(const float* __restrict__ W, ushort* __restrict__ WT,
                              int Kd, int N) {
    __shared__ float t[32][33];
    int k0 = blockIdx.x * 32, n0 = blockIdx.y * 32;
    int tx = threadIdx.x, ty = threadIdx.y;
    for (int i = ty; i < 32; i += 8) {
        int n = n0 + tx;
        t[i][tx] = (n < N) ? W[(size_t)(k0 + i) * N + n] : 0.f;
    }
    __syncthreads();
    for (int i = ty; i < 32; i += 8) {
        int n = n0 + i;
        if (n < N) WT[(size_t)n * Kd + k0 + tx] = f2bf(t[tx][i]);
    }
}

// ---------------------------------------------------------------------------
// normalize cluster embeds rows, write transposed cnT[h][k]
// ---------------------------------------------------------------------------
__global__ void cn_norm_kernel(const float* __restrict__ ce, float* __restrict__ cnT) {
    int k = blockIdx.x, h = threadIdx.x;
    float v = ce[(size_t)k * HH + h];
    __shared__ float sh[128];
    sh[h] = v * v;
    __syncthreads();
    for (int o = 64; o >= 1; o >>= 1) {
        if (h < o) sh[h] += sh[h + o];
        __syncthreads();
    }
    float nrm = sqrtf(sh[0]) + 1e-8f;
    cnT[(size_t)h * KK + k] = v / nrm;
}

// per-token 1/(||h||+1e-8)
__global__ void rownorm_kernel(const float* __restrict__ h, float* __restrict__ rn) {
    size_t row = (size_t)blockIdx.x * 256 + threadIdx.x;
    const float4* hp = (const float4*)(h + row * HH);
    float s = 0.f;
    #pragma unroll
    for (int i = 0; i < 32; ++i) {
        float4 v = hp[i];
        s += v.x * v.x + v.y * v.y + v.z * v.z + v.w * v.w;
    }
    rn[row] = 1.f / (sqrtf(s) + 1e-8f);
}

// Qp[k,h'] = (sum_h wk_w[h',h] * Q[k,h]) / sqrt(H);  qb[k] = (Q[k].wk_b)/sqrt(H)
__global__ void qprime_kernel(const float* __restrict__ Q, const float* __restrict__ wk_w,
                              const float* __restrict__ wk_b, float* __restrict__ Qp,
                              float* __restrict__ qb) {
    int k = blockIdx.x;
    int hp = threadIdx.x;
    __shared__ float qrow[128];
    __shared__ float red[128];
    qrow[hp] = Q[(size_t)k * HH + hp];
    __syncthreads();
    float s = 0.f;
    for (int h = 0; h < HH; ++h) s = fmaf(qrow[h], wk_w[(size_t)hp * HH + h], s);
    const float rs = 0.088388347648318447f;
    Qp[(size_t)k * HH + hp] = s * rs;
    red[hp] = qrow[hp] * wk_b[hp];
    __syncthreads();
    for (int o = 64; o >= 1; o >>= 1) {
        if (hp < o) red[hp] += red[hp + o];
        __syncthreads();
    }
    if (hp == 0) qb[k] = red[0] * rs;
}

// ---------------------------------------------------------------------------
// softmax over K=64, Bernoulli mask (u8, [B,K,L]), p-mean partials
// ---------------------------------------------------------------------------
__global__ __launch_bounds__(256)
void pmask_kernel(const float* __restrict__ sp, const float* __restrict__ rn,
                  const float* __restrict__ bern, unsigned char* __restrict__ Mt,
                  float* __restrict__ ppart) {
    int b = blockIdx.y;
    int l0 = blockIdx.x * 32;
    int tid = threadIdx.x;
    int wv = tid >> 6, lane = tid & 63;
    __shared__ float Msh[64][33];
    __shared__ float psum[4][64];
    float pa = 0.f;
    for (int tt = 0; tt < 8; ++tt) {
        int l = l0 + wv * 8 + tt;
        size_t tok = (size_t)b * LL + l;
        float s = sp[tok * 64 + lane] * rn[tok];
        float mx = s;
        #pragma unroll
        for (int o = 32; o >= 1; o >>= 1) mx = fmaxf(mx, __shfl_xor(mx, o));
        float ev = expf(s - mx);
        float sm = ev;
        #pragma unroll
        for (int o = 32; o >= 1; o >>= 1) sm += __shfl_xor(sm, o);
        float p = ev / sm;
        pa += p;
        Msh[lane][wv * 8 + tt] = (bern[tok * KK + lane] < p) ? 1.f : 0.f;
    }
    psum[wv][lane] = pa;
    __syncthreads();
    for (int q = tid; q < 64 * 32; q += 256) {
        int k = q >> 5, j = q & 31;
        Mt[((size_t)b * KK + k) * LL + l0 + j] = (unsigned char)Msh[k][j];
    }
    if (tid < 64)
        ppart[((size_t)b * (LL / 32) + blockIdx.x) * KK + tid] =
            psum[0][tid] + psum[1][tid] + psum[2][tid] + psum[3][tid];
}

__global__ void pmean_final_kernel(const float* __restrict__ part, float* __restrict__ pm) {
    int b = blockIdx.x, k = threadIdx.x;
    float s = 0.f;
    for (int i = 0; i < LL / 32; ++i) s += part[((size_t)b * (LL / 32) + i) * KK + k];
    pm[b * KK + k] = s * (1.f / LL);
}

// ---------------------------------------------------------------------------
// scores[b,k,l] = Qp[k,:].h[b,l,:] + qb[k]
// ---------------------------------------------------------------------------
__global__ __launch_bounds__(256)
void scores_kernel(const float* __restrict__ Qp, const float* __restrict__ hmat,
                   const float* __restrict__ qb, float* __restrict__ S) {
    __shared__ float QT[128][64];
    __shared__ float KT[32][128];
    int tid = threadIdx.x;
    int b = blockIdx.y;
    int l0 = blockIdx.x * 128;
    for (int q = tid; q < 64 * 128; q += 256) {
        int k = q >> 7, h = q & 127;
        QT[h][k] = Qp[q];
    }
    int tx = tid & 15, ty = tid >> 4;
    float acc[4][8] = {};
    const float* Kb = hmat + (size_t)b * LL * HH;
    for (int ht = 0; ht < HH; ht += 32) {
        __syncthreads();
        #pragma unroll
        for (int it = 0; it < 4; ++it) {
            int q = tid + it * 256;
            int row = q >> 3;
            int hq = (q & 7) << 2;
            float4 v = *(const float4*)(Kb + (size_t)(l0 + row) * HH + ht + hq);
            KT[hq][row] = v.x; KT[hq + 1][row] = v.y;
            KT[hq + 2][row] = v.z; KT[hq + 3][row] = v.w;
        }
        __syncthreads();
        #pragma unroll
        for (int h = 0; h < 32; ++h) {
            float qv[4], kv[8];
            *(float4*)&qv[0] = *(const float4*)&QT[ht + h][ty * 4];
            *(float4*)&kv[0] = *(const float4*)&KT[h][tx * 4];
            *(float4*)&kv[4] = *(const float4*)&KT[h][64 + tx * 4];
            #pragma unroll
            for (int i = 0; i < 4; ++i)
                #pragma unroll
                for (int j = 0; j < 8; ++j)
                    acc[i][j] = fmaf(qv[i], kv[j], acc[i][j]);
        }
    }
    #pragma unroll
    for (int i = 0; i < 4; ++i) {
        int k = ty * 4 + i;
        float bq = qb[k];
        #pragma unroll
        for (int jj = 0; jj < 8; jj += 4) {
            int l = l0 + (jj ? 64 + tx * 4 : tx * 4);
            float o[4];
            #pragma unroll
            for (int j = 0; j < 4; ++j) o[j] = acc[i][jj + j] + bq;
            *(float4*)(S + ((size_t)b * KK + k) * LL + l) = *(float4*)o;
        }
    }
}

// ---------------------------------------------------------------------------
// aw = softmax_l( exp(scores) * Mt ), in place on S
// ---------------------------------------------------------------------------
__global__ __launch_bounds__(256)
void aw_kernel(float* __restrict__ S, const unsigned char* __restrict__ Mt) {
    size_t base = (size_t)blockIdx.x * LL;
    int tid = threadIdx.x;
    float t[8];
    float mx = -1e30f;
    #pragma unroll
    for (int i = 0; i < 8; ++i) {
        int l = tid + i * 256;
        float v = expf(S[base + l]) * (float)Mt[base + l];
        t[i] = v;
        mx = fmaxf(mx, v);
    }
    __shared__ float shA[4];
    __shared__ float shB[4];
    #pragma unroll
    for (int o = 32; o >= 1; o >>= 1) mx = fmaxf(mx, __shfl_xor(mx, o));
    if ((tid & 63) == 0) shA[tid >> 6] = mx;
    __syncthreads();
    mx = fmaxf(fmaxf(shA[0], shA[1]), fmaxf(shA[2], shA[3]));
    float e[8];
    float sum = 0.f;
    #pragma unroll
    for (int i = 0; i < 8; ++i) { e[i] = expf(t[i] - mx); sum += e[i]; }
    #pragma unroll
    for (int o = 32; o >= 1; o >>= 1) sum += __shfl_xor(sum, o);
    if ((tid & 63) == 0) shB[tid >> 6] = sum;
    __syncthreads();
    sum = (shB[0] + shB[1]) + (shB[2] + shB[3]);
    float inv = 1.f / sum;
    #pragma unroll
    for (int i = 0; i < 8; ++i) S[base + tid + i * 256] = e[i] * inv;
}

// ---------------------------------------------------------------------------
// awh split-L partials
// ---------------------------------------------------------------------------
__global__ __launch_bounds__(256)
void awh_part_kernel(const float* __restrict__ AWs, const float* __restrict__ hmat,
                     float* __restrict__ part) {
    __shared__ float AT[32][64];
    __shared__ float VT[32][128];
    int b = blockIdx.y, sp = blockIdx.x;
    int tid = threadIdx.x;
    int tx = tid & 15, ty = tid >> 4;
    float acc[4][8] = {};
    const float* Ab = AWs + (size_t)b * KK * LL + sp * 512;
    const float* Vb = hmat + ((size_t)b * LL + sp * 512) * HH;
    for (int lt = 0; lt < 512; lt += 32) {
        __syncthreads();
        #pragma unroll
        for (int it = 0; it < 2; ++it) {
            int q = tid + it * 256;
            int row = q >> 3;
            int lq = (q & 7) << 2;
            float4 v = *(const float4*)(Ab + (size_t)row * LL + lt + lq);
            AT[lq][row] = v.x; AT[lq + 1][row] = v.y;
            AT[lq + 2][row] = v.z; AT[lq + 3][row] = v.w;
        }
        #pragma unroll
        for (int it = 0; it < 4; ++it) {
            int q = tid + it * 256;
            int lr = q >> 5;
            int hc = (q & 31) << 2;
            *(float4*)&VT[lr][hc] = *(const float4*)(Vb + (size_t)(lt + lr) * HH + hc);
        }
        __syncthreads();
        #pragma unroll
        for (int l = 0; l < 32; ++l) {
            float av[4], vv[8];
            *(float4*)&av[0] = *(const float4*)&AT[l][ty * 4];
            *(float4*)&vv[0] = *(const float4*)&VT[l][tx * 4];
            *(float4*)&vv[4] = *(const float4*)&VT[l][64 + tx * 4];
            #pragma unroll
            for (int i = 0; i < 4; ++i)
                #pragma unroll
                for (int j = 0; j < 8; ++j)
                    acc[i][j] = fmaf(av[i], vv[j], acc[i][j]);
        }
    }
    #pragma unroll
    for (int i = 0; i < 4; ++i) {
        int k = ty * 4 + i;
        #pragma unroll
        for (int jj = 0; jj < 8; jj += 4) {
            int h = (jj ? 64 + tx * 4 : tx * 4);
            float o[4];
            #pragma unroll
            for (int j = 0; j < 4; ++j) o[j] = acc[i][jj + j];
            *(float4*)(part + (((size_t)b * 4 + sp) * KK + k) * HH + h) = *(float4*)o;
        }
    }
}

__global__ void awh_reduce_kernel(const float* __restrict__ part, float* __restrict__ awh) {
    int bk = blockIdx.x, h = threadIdx.x;
    int b = bk >> 6, k = bk & 63;
    float s = 0.f;
    #pragma unroll
    for (int sp = 0; sp < 4; ++sp)
        s += part[(((size_t)b * 4 + sp) * KK + k) * HH + h];
    awh[(size_t)bk * HH + h] = s;
}

__global__ void newce_kernel(const float* __restrict__ ao, const float* __restrict__ pm,
                             float* __restrict__ outTail) {
    int k = blockIdx.x, h = threadIdx.x;
    float s = 0.f;
    for (int b = 0; b < BB; ++b)
        s += ao[((size_t)b * KK + k) * HH + h] * pm[b * KK + k];
    outTail[(size_t)k * HH + h] = s * (1.f / BB);
}

__global__ void revin_apply_kernel(float* __restrict__ z,
                                   const float* __restrict__ mu, const float* __restrict__ rs) {
    size_t total = (size_t)BB * LL * CC;
    for (size_t i = (size_t)blockIdx.x * 256 + threadIdx.x; i < total;
         i += (size_t)gridDim.x * 256) {
        size_t b = i / ((size_t)LL * CC);
        int c = (int)(i & 127);
        z[i] = (z[i] - mu[b * CC + c]) * rs[b * CC + c];
    }
}

// timestep BN stats: per l over (b, c)
__global__ __launch_bounds__(256)
void bnt_stats_kernel(const float* __restrict__ z, float* __restrict__ mu,
                      float* __restrict__ rv) {
    int l = blockIdx.x;
    int tid = threadIdx.x;
    float s = 0.f, s2 = 0.f;
    for (int i = tid; i < BB * CC; i += 256) {
        int b = i >> 7, c = i & 127;
        float v = z[((size_t)b * LL + l) * CC + c];
        s += v; s2 += v * v;
    }
    #pragma unroll
    for (int o = 32; o >= 1; o >>= 1) { s += __shfl_xor(s, o); s2 += __shfl_xor(s2, o); }
    __shared__ float shA[4];
    __shared__ float shB[4];
    if ((tid & 63) == 0) { shA[tid >> 6] = s; shB[tid >> 6] = s2; }
    __syncthreads();
    if (tid == 0) {
        float ts = (shA[0] + shA[1]) + (shA[2] + shA[3]);
        float tq = (shB[0] + shB[1]) + (shB[2] + shB[3]);
        float m = ts / (float)(BB * CC);
        float var = tq / (float)(BB * CC) - m * m;
        var = fmaxf(var, 0.f);
        mu[l] = m;
        rv[l] = 1.f / sqrtf(var + EPSf);
    }
}

// [B,L,C] f32 -> [B,C,L] bf16, optional timestep-BN on the fly
template <bool DO_BN>
__global__ void transpose_bn_kernel(const float* __restrict__ in, ushort* __restrict__ out,
                                    const float* __restrict__ mu, const float* __restrict__ rv,
                                    const float* __restrict__ g, const float* __restrict__ be) {
    __shared__ float tile[32][33];
    int l0 = blockIdx.x * 32, c0 = blockIdx.y * 32, b = blockIdx.z;
    int tx = threadIdx.x, ty = threadIdx.y;
    const float* ib = in + (size_t)b * LL * CC;
    for (int i = ty; i < 32; i += 8) {
        int l = l0 + i;
        float v = ib[(size_t)l * CC + c0 + tx];
        if (DO_BN) v = (v - mu[l]) * rv[l] * g[l] + be[l];
        tile[i][tx] = v;
    }
    __syncthreads();
    ushort* ob = out + (size_t)b * CC * LL;
    for (int i = ty; i < 32; i += 8)
        ob[(size_t)(c0 + i) * LL + l0 + tx] = f2bf(tile[tx][i]);
}

// feature BN partial stats
__global__ void bnf_part_kernel(const float* __restrict__ z, float* __restrict__ part) {
    int c = threadIdx.x;
    const int rows = (BB * LL) / 1024;
    size_t r0 = (size_t)blockIdx.x * rows;
    float s = 0.f, s2 = 0.f;
    for (int r = 0; r < rows; ++r) {
        float v = z[(r0 + r) * CC + c];
        s += v; s2 += v * v;
    }
    part[(size_t)blockIdx.x * 256 + c] = s;
    part[(size_t)blockIdx.x * 256 + 128 + c] = s2;
}

__global__ void bnf_final_kernel(const float* __restrict__ part, const float* __restrict__ g,
                                 const float* __restrict__ be, float* __restrict__ mu,
                                 float* __restrict__ sA, float* __restrict__ tA) {
    int c = threadIdx.x;
    float s = 0.f, s2 = 0.f;
    for (int i = 0; i < 1024; ++i) {
        s += part[(size_t)i * 256 + c];
        s2 += part[(size_t)i * 256 + 128 + c];
    }
    float m = s / (float)(BB * LL);
    float var = s2 / (float)(BB * LL) - m * m;
    var = fmaxf(var, 0.f);
    float rvv = 1.f / sqrtf(var + EPSf);
    mu[c] = m;
    sA[c] = rvv * g[c];
    tA[c] = be[c];
}

// ---------------------------------------------------------------------------
extern "C" void kernel_launch(void* const* d_in, const int* in_sizes, int n_in,
                              void* d_out, int out_size, void* d_ws, size_t ws_size,
                              hipStream_t stream) {
    const float* x     = (const float*)d_in[0];
    const float* bern  = (const float*)d_in[1];
    const float* ce    = (const float*)d_in[2];
    const float* wq_w  = (const float*)d_in[3];
    const float* wq_b  = (const float*)d_in[4];
    const float* wk_w  = (const float*)d_in[5];
    const float* wk_b  = (const float*)d_in[6];
    const float* wv_w  = (const float*)d_in[7];
    const float* wv_b  = (const float*)d_in[8];
    const float* cm_w1 = (const float*)d_in[9];
    const float* cm_b1 = (const float*)d_in[10];
    const float* cm_w2 = (const float*)d_in[11];
    const float* cm_b2 = (const float*)d_in[12];
    const float* tm_w1 = (const float*)d_in[13];
    const float* tm_b1 = (const float*)d_in[14];
    const float* tm_w2 = (const float*)d_in[15];
    const float* tm_b2 = (const float*)d_in[16];
    const float* bn_t_g = (const float*)d_in[17];
    const float* bn_t_b = (const float*)d_in[18];
    const float* lin_t_w = (const float*)d_in[19];
    const float* lin_t_b = (const float*)d_in[20];
    const float* bn_f_g = (const float*)d_in[21];
    const float* bn_f_b = (const float*)d_in[22];
    const float* f1_w  = (const float*)d_in[23];
    const float* f1_b  = (const float*)d_in[24];
    const float* f2_w  = (const float*)d_in[25];
    const float* f2_b  = (const float*)d_in[26];
    const float* out_w = (const float*)d_in[27];
    const float* out_b = (const float*)d_in[28];
    (void)in_sizes; (void)n_in; (void)out_size;

    float* y = (float*)d_out;                         // [B,P,C]
    float* ceOut = y + (size_t)BB * PP * CC;          // [K,H]

    float* ws = (float*)d_ws;
    size_t off = 0;
    auto alloc = [&](size_t n) { float* p = ws + off; off += n; return p; };
    float* mean1  = alloc(BB * CC);
    float* rstd1  = alloc(BB * CC);
    float* std1   = alloc(BB * CC);
    float* mean2  = alloc(BB * CC);
    float* rstd2  = alloc(BB * CC);
    float* std2   = alloc(BB * CC);
    float* bnmu   = alloc(LL);
    float* bnrv   = alloc(LL);
    float* bfpart = alloc(1024 * 256);
    float* bfmu   = alloc(CC);
    float* bfs    = alloc(CC);
    float* bft    = alloc(CC);
    float* qbuf   = alloc(KK * HH);
    float* qp     = alloc(KK * HH);
    float* qb     = alloc(KK);
    float* cnT    = alloc(HH * KK);
    float* rn     = alloc((size_t)BB * LL);
    float* ppart  = alloc((size_t)BB * (LL / 32) * KK);
    float* pmean  = alloc(BB * KK);
    float* awhprt = alloc((size_t)BB * 4 * KK * HH);
    float* awh    = alloc((size_t)BB * KK * HH);
    float* aobuf  = alloc((size_t)BB * KK * HH);
    ushort* wtT   = (ushort*)alloc((size_t)LL * LL / 2);      // lin_t_w^T bf16
    ushort* owT   = (ushort*)alloc((size_t)PP * LL / 2 + 64); // out_w^T bf16
    float* S      = alloc((size_t)BB * KK * LL);
    float* buf0   = alloc((size_t)BB * LL * CC);
    float* buf2   = alloc((size_t)BB * LL * CC);
    unsigned char* Mt = (unsigned char*)(ws + off);           // [B,K,L] u8
    ushort* abf = (ushort*)S;   // bf16 [B,C,L] overlay on S (dead by mixer time)
    (void)ws_size;

    const int ML = BB * LL;      // 131072
    dim3 g1024(1, ML / 128);
    dim3 tb(32, 8);
    dim3 tgrid(LL / 32, CC / 32, BB);

    // 0) weight transpose+bf16 (independent of activations)
    wtrans_kernel<<<dim3(LL / 32, LL / 32), tb, 0, stream>>>(lin_t_w, wtT, LL, LL);
    wtrans_kernel<<<dim3(LL / 32, (PP + 31) / 32), tb, 0, stream>>>(out_w, owT, LL, PP);

    // 1) RevIN-1 stats
    colstats_kernel<<<dim3(BB), dim3(128, 8), 0, stream>>>(x, mean1, rstd1, std1);
    // 2) buf0 = relu(norm(x) @ cm_w1 + cm_b1)
    gemm_kernel<1, 1, 0><<<g1024, 256, 0, stream>>>(x, cm_w1, cm_b1, buf0,
        ML, HH, CC, CC, HH, HH, mean1, rstd1, nullptr, CC);
    // 3) h = buf2
    gemm_kernel<0, 0, 0><<<g1024, 256, 0, stream>>>(buf0, cm_w2, cm_b2, buf2,
        ML, HH, HH, HH, HH, HH, nullptr, nullptr, nullptr, 0);
    // 4) Q, Qp, qb
    gemm_kernel<0, 0, 0><<<dim3(1, 1), 256, 0, stream>>>(ce, wq_w, wq_b, qbuf,
        KK, HH, HH, HH, HH, HH, nullptr, nullptr, nullptr, 0);
    qprime_kernel<<<dim3(KK), dim3(128), 0, stream>>>(qbuf, wk_w, wk_b, qp, qb);
    // 5) normalized codebook
    cn_norm_kernel<<<dim3(KK), dim3(128), 0, stream>>>(ce, cnT);
    // 6) token norms
    rownorm_kernel<<<dim3(ML / 256), 256, 0, stream>>>(buf2, rn);
    // 7) routing scores
    gemm_kernel<0, 0, 0><<<g1024, 256, 0, stream>>>(buf2, cnT, nullptr, S,
        ML, KK, HH, HH, KK, KK, nullptr, nullptr, nullptr, 0);
    // 8) softmax/mask/p-mean
    pmask_kernel<<<dim3(LL / 32, BB), 256, 0, stream>>>(S, rn, bern, Mt, ppart);
    pmean_final_kernel<<<dim3(BB), dim3(64), 0, stream>>>(ppart, pmean);
    // 9) attn scores
    scores_kernel<<<dim3(LL / 128, BB), 256, 0, stream>>>(qp, buf2, qb, S);
    // 10) masked double-exp softmax
    aw_kernel<<<dim3(BB * KK), 256, 0, stream>>>(S, Mt);
    // 11) awh -> ao -> cluster update
    awh_part_kernel<<<dim3(4, BB), 256, 0, stream>>>(S, buf2, awhprt);
    awh_reduce_kernel<<<dim3(BB * KK), dim3(128), 0, stream>>>(awhprt, awh);
    gemm_kernel<0, 0, 0><<<dim3(1, (BB * KK) / 128), 256, 0, stream>>>(awh, wv_w, wv_b, aobuf,
        BB * KK, HH, HH, HH, HH, HH, nullptr, nullptr, nullptr, 0);
    newce_kernel<<<dim3(KK), dim3(128), 0, stream>>>(aobuf, pmean, ceOut);
    // 12) temporal module
    gemm_kernel<0, 1, 0><<<g1024, 256, 0, stream>>>(buf2, tm_w1, tm_b1, buf0,
        ML, HH, HH, HH, HH, HH, nullptr, nullptr, nullptr, 0);
    gemm_kernel<0, 0, 0><<<g1024, 256, 0, stream>>>(buf0, tm_w2, tm_b2, buf2,
        ML, HH, HH, HH, HH, HH, nullptr, nullptr, nullptr, 0);
    // 13) RevIN-2 stats + apply (z in buf2)
    colstats_kernel<<<dim3(BB), dim3(128, 8), 0, stream>>>(buf2, mean2, rstd2, std2);
    revin_apply_kernel<<<dim3(2048), 256, 0, stream>>>(buf2, mean2, rstd2);
    // 14) 4 mixer blocks
    for (int blkI = 0; blkI < 4; ++blkI) {
        bnt_stats_kernel<<<dim3(LL), 256, 0, stream>>>(buf2, bnmu, bnrv);
        transpose_bn_kernel<true><<<tgrid, tb, 0, stream>>>(buf2, abf, bnmu, bnrv, bn_t_g, bn_t_b);
        // timestep MFMA GEMM: gelu + transposed residual add into z
        mfma_gemm_kernel<1><<<dim3(LL / 128, (BB * CC) / 128), 256, 0, stream>>>(
            abf, wtT, lin_t_b, buf2, BB * CC, LL, LL, LL, nullptr, nullptr);
        bnf_part_kernel<<<dim3(1024), dim3(128), 0, stream>>>(buf2, bfpart);
        bnf_final_kernel<<<dim3(1), dim3(128), 0, stream>>>(bfpart, bn_f_g, bn_f_b, bfmu, bfs, bft);
        gemm_kernel<2, 2, 0><<<g1024, 256, 0, stream>>>(buf2, f1_w, f1_b, buf0,
            ML, HH, CC, CC, HH, HH, bfmu, bfs, bft, 0);
        gemm_kernel<0, 0, 1><<<g1024, 256, 0, stream>>>(buf0, f2_w, f2_b, buf2,
            ML, CC, HH, HH, CC, CC, nullptr, nullptr, nullptr, 0);
    }
    // 15) head via MFMA: y[b,p,c] = (z^T @ out_w + out_b) * std2 + mean2
    transpose_bn_kernel<false><<<tgrid, tb, 0, stream>>>(buf2, abf,
        nullptr, nullptr, nullptr, nullptr);
    mfma_gemm_kernel<2><<<dim3((PP + 127) / 128, (BB * CC) / 128), 256, 0, stream>>>(
        abf, owT, out_b, y, BB * CC, PP, LL, PP, std2, mean2);
}

// Round 5
// 1956.196 us; speedup vs baseline: 2.9667x; 1.2066x over previous
//
#include <hip/hip_runtime.h>
#include <math.h>

#define BB 64
#define LL 2048
#define CC 128
#define HH 128
#define KK 64
#define PP 336
#define EPSf 1e-5f

typedef __attribute__((ext_vector_type(8))) short short8v;
typedef __attribute__((ext_vector_type(4))) float float4v;

__device__ inline ushort f2bf(float f) {
    union { float f; unsigned u; } v; v.f = f;
    unsigned r = (v.u + 0x7FFFu + ((v.u >> 16) & 1u)) >> 16;
    return (ushort)r;
}
__device__ inline float bf2f(ushort h) {
    union { unsigned u; float f; } v; v.u = ((unsigned)h) << 16;
    return v.f;
}

// ---------------------------------------------------------------------------
// RevIN column stats over L for [B, L, 128]: mean/rstd/std per (b, c)
// ---------------------------------------------------------------------------
__global__ void colstats_kernel(const float* __restrict__ x, float* __restrict__ mean,
                                float* __restrict__ rstd, float* __restrict__ stdv) {
    int b = blockIdx.x;
    int c = threadIdx.x;
    int j = threadIdx.y;
    const float* xb = x + (size_t)b * LL * CC;
    float s = 0.f, s2 = 0.f;
    for (int l = j; l < LL; l += 8) {
        float v = xb[(size_t)l * CC + c];
        s += v; s2 += v * v;
    }
    __shared__ float shs[8][128];
    __shared__ float shq[8][128];
    shs[j][c] = s; shq[j][c] = s2;
    __syncthreads();
    if (j == 0) {
        float ts = 0.f, tq = 0.f;
        for (int i = 0; i < 8; ++i) { ts += shs[i][c]; tq += shq[i][c]; }
        float mu = ts * (1.f / LL);
        float var = tq * (1.f / LL) - mu * mu;
        var = fmaxf(var, 0.f);
        float sd = sqrtf(var + EPSf);
        mean[b * CC + c] = mu;
        stdv[b * CC + c] = sd;
        rstd[b * CC + c] = 1.f / sd;
    }
}

// ---------------------------------------------------------------------------
// plain f32 VALU GEMM (only for tiny Q-GEMM and the N=64 routing-scores GEMM)
// ---------------------------------------------------------------------------
__global__ __launch_bounds__(256)
void gemm_kernel(const float* __restrict__ A, const float* __restrict__ W,
                 const float* __restrict__ bias, float* __restrict__ Out,
                 int M, int N, int Kd, int lda, int ldw, int ldo) {
    __shared__ float As[32][128];
    __shared__ float Ws[32][128];
    int tid = threadIdx.x;
    int tx = tid & 15, ty = tid >> 4;
    int n0 = blockIdx.x * 128;
    int m0 = blockIdx.y * 128;
    float acc[8][8] = {};

    for (int kt = 0; kt < Kd; kt += 32) {
        __syncthreads();
        #pragma unroll
        for (int it = 0; it < 4; ++it) {
            int q = tid + it * 256;
            int row = q >> 3;
            int kq = (q & 7) << 2;
            float4 v = make_float4(0.f, 0.f, 0.f, 0.f);
            int m = m0 + row;
            if (m < M) v = *(const float4*)(A + (size_t)m * lda + kt + kq);
            As[kq    ][row] = v.x;
            As[kq + 1][row] = v.y;
            As[kq + 2][row] = v.z;
            As[kq + 3][row] = v.w;
        }
        #pragma unroll
        for (int it = 0; it < 4; ++it) {
            int q = tid + it * 256;
            int kr = q >> 5;
            int nc = (q & 31) << 2;
            int n = n0 + nc;
            float4 v = make_float4(0.f, 0.f, 0.f, 0.f);
            if (n < N) v = *(const float4*)(W + (size_t)(kt + kr) * ldw + n);
            *(float4*)&Ws[kr][nc] = v;
        }
        __syncthreads();
        #pragma unroll
        for (int k = 0; k < 32; ++k) {
            float a[8], w[8];
            *(float4*)&a[0] = *(const float4*)&As[k][ty * 8];
            *(float4*)&a[4] = *(const float4*)&As[k][ty * 8 + 4];
            *(float4*)&w[0] = *(const float4*)&Ws[k][tx * 4];
            *(float4*)&w[4] = *(const float4*)&Ws[k][64 + tx * 4];
            #pragma unroll
            for (int i = 0; i < 8; ++i)
                #pragma unroll
                for (int j = 0; j < 8; ++j)
                    acc[i][j] = fmaf(a[i], w[j], acc[i][j]);
        }
    }

    #pragma unroll
    for (int i = 0; i < 8; ++i) {
        int m = m0 + ty * 8 + i;
        if (m >= M) continue;
        #pragma unroll
        for (int jj = 0; jj < 8; jj += 4) {
            int n = n0 + (jj ? 64 + tx * 4 : tx * 4);
            if (n >= N) continue;
            float o[4];
            #pragma unroll
            for (int j = 0; j < 4; ++j)
                o[j] = acc[i][jj + j] + (bias ? bias[n + j] : 0.f);
            *(float4*)(Out + (size_t)m * ldo + n) = *(float4*)o;
        }
    }
}

// ---------------------------------------------------------------------------
// Split-precision MFMA GEMM for N=K=128 (lda=ldo=128):
// A f32 -> (hi,lo) bf16 in-kernel; W pre-split bf16 [n][k].
// acc = ahi*bhi + ahi*blo + alo*bhi  (~f32 accuracy)
// Two K-tiles of 64 staged into [128][72] LDS (fits the padded stride).
// NORM: 0 none; 1 RevIN per-(b,k); 2 BN affine per-k.  ACT: 0/1 relu/2 gelu.
// EP: 0 store, 1 residual +=.
// ---------------------------------------------------------------------------
template <int NORM, int ACT, int EP>
__global__ __launch_bounds__(256)
void mfma_sq_kernel(const float* __restrict__ A, const ushort* __restrict__ Whi,
                    const ushort* __restrict__ Wlo, const float* __restrict__ bias,
                    float* Out,
                    const float* __restrict__ nmu, const float* __restrict__ ns,
                    const float* __restrict__ nt, int normStride) {
    __shared__ ushort Ahi[128][72];
    __shared__ ushort Alo[128][72];
    __shared__ ushort Bhi[128][72];
    __shared__ ushort Blo[128][72];
    int tid = threadIdx.x;
    int m0 = blockIdx.x * 128;
    int noff = (NORM == 1) ? (m0 / LL) * normStride : 0;

    int w = tid >> 6, lane = tid & 63;
    int wm = (w >> 1) * 64, wn = (w & 1) * 64;
    int col = lane & 15, kq = lane >> 4;

    float4v acc[4][4];
    #pragma unroll
    for (int i = 0; i < 4; ++i)
        #pragma unroll
        for (int j = 0; j < 4; ++j) acc[i][j] = (float4v){0.f, 0.f, 0.f, 0.f};

    for (int kt = 0; kt < 2; ++kt) {
        __syncthreads();
        #pragma unroll
        for (int it = 0; it < 4; ++it) {
            int q = tid + it * 256;
            int row = q >> 3, k0 = (q & 7) * 8;   // k0 in [0,56]
            int kg = kt * 64 + k0;
            const float* ap = A + (size_t)(m0 + row) * 128 + kg;
            float vv[8];
            *(float4*)&vv[0] = *(const float4*)ap;
            *(float4*)&vv[4] = *(const float4*)(ap + 4);
            ushort hi[8], lo[8];
            #pragma unroll
            for (int j = 0; j < 8; ++j) {
                float v = vv[j];
                if (NORM == 1) v = (v - nmu[noff + kg + j]) * ns[noff + kg + j];
                if (NORM == 2) v = (v - nmu[kg + j]) * ns[kg + j] + nt[kg + j];
                ushort h = f2bf(v);
                hi[j] = h;
                lo[j] = f2bf(v - bf2f(h));
            }
            *(short8v*)&Ahi[row][k0] = *(short8v*)hi;
            *(short8v*)&Alo[row][k0] = *(short8v*)lo;
        }
        #pragma unroll
        for (int it = 0; it < 4; ++it) {
            int q = tid + it * 256;
            int row = q >> 3, k0 = (q & 7) * 8;
            *(short8v*)&Bhi[row][k0] =
                *(const short8v*)(Whi + (size_t)row * 128 + kt * 64 + k0);
            *(short8v*)&Blo[row][k0] =
                *(const short8v*)(Wlo + (size_t)row * 128 + kt * 64 + k0);
        }
        __syncthreads();
        #pragma unroll
        for (int ksub = 0; ksub < 2; ++ksub) {
            short8v ah[4], al[4], bh[4], bl[4];
            #pragma unroll
            for (int mf = 0; mf < 4; ++mf) {
                ah[mf] = *(const short8v*)&Ahi[wm + mf * 16 + col][ksub * 32 + kq * 8];
                al[mf] = *(const short8v*)&Alo[wm + mf * 16 + col][ksub * 32 + kq * 8];
            }
            #pragma unroll
            for (int nf = 0; nf < 4; ++nf) {
                bh[nf] = *(const short8v*)&Bhi[wn + nf * 16 + col][ksub * 32 + kq * 8];
                bl[nf] = *(const short8v*)&Blo[wn + nf * 16 + col][ksub * 32 + kq * 8];
            }
            #pragma unroll
            for (int mf = 0; mf < 4; ++mf)
                #pragma unroll
                for (int nf = 0; nf < 4; ++nf)
                    acc[mf][nf] = __builtin_amdgcn_mfma_f32_16x16x32_bf16(
                        ah[mf], bh[nf], acc[mf][nf], 0, 0, 0);
            #pragma unroll
            for (int mf = 0; mf < 4; ++mf)
                #pragma unroll
                for (int nf = 0; nf < 4; ++nf)
                    acc[mf][nf] = __builtin_amdgcn_mfma_f32_16x16x32_bf16(
                        ah[mf], bl[nf], acc[mf][nf], 0, 0, 0);
            #pragma unroll
            for (int mf = 0; mf < 4; ++mf)
                #pragma unroll
                for (int nf = 0; nf < 4; ++nf)
                    acc[mf][nf] = __builtin_amdgcn_mfma_f32_16x16x32_bf16(
                        al[mf], bh[nf], acc[mf][nf], 0, 0, 0);
        }
    }

    int rbase = kq * 4;
    #pragma unroll
    for (int nf = 0; nf < 4; ++nf) {
        int n = wn + nf * 16 + col;
        float bn = bias[n];
        #pragma unroll
        for (int mf = 0; mf < 4; ++mf) {
            #pragma unroll
            for (int r = 0; r < 4; ++r) {
                int m = m0 + wm + mf * 16 + rbase + r;
                float v = acc[mf][nf][r] + bn;
                if (ACT == 1) v = fmaxf(v, 0.f);
                if (ACT == 2) v = 0.5f * v * (1.f + erff(v * 0.70710678118654752f));
                if (EP == 0) Out[(size_t)m * 128 + n] = v;
                else Out[(size_t)m * 128 + n] += v;
            }
        }
    }
}

// W [128][128] f32 -> Whi/Wlo [n][k] bf16 split (transposed). grid (4,4), block (32,8)
__global__ void wsplit_kernel(const float* __restrict__ W, ushort* __restrict__ Whi,
                              ushort* __restrict__ Wlo) {
    __shared__ float t[32][33];
    int k0 = blockIdx.x * 32, n0 = blockIdx.y * 32;
    int tx = threadIdx.x, ty = threadIdx.y;
    for (int i = ty; i < 32; i += 8)
        t[i][tx] = W[(size_t)(k0 + i) * 128 + n0 + tx];
    __syncthreads();
    for (int i = ty; i < 32; i += 8) {
        float v = t[tx][i];
        ushort h = f2bf(v);
        Whi[(size_t)(n0 + i) * 128 + k0 + tx] = h;
        Wlo[(size_t)(n0 + i) * 128 + k0 + tx] = f2bf(v - bf2f(h));
    }
}

// ---------------------------------------------------------------------------
// bf16 MFMA GEMM (big-K): A [M][K] bf16, W [N][K] bf16. 128x128 tile, BK=64.
// EPM=1: v=gelu(acc+bias[n]); Z[(b*LDO+n)*128+c] += v   (m = b*128+c)
// EPM=2: v=acc+bias[n];       Z[(b*LDO+n)*128+c] = v*epS[m]+epM[m]
// 1D grid with XCD swizzle (nwg % 8 == 0), n-fast decode.
// ---------------------------------------------------------------------------
template <int EPM>
__global__ __launch_bounds__(256)
void mfma_gemm_kernel(const ushort* __restrict__ A, const ushort* __restrict__ W,
                      const float* __restrict__ bias, float* Z,
                      int N, int Kd, int LDO, int nx, int nwg,
                      const float* __restrict__ epS, const float* __restrict__ epM) {
    __shared__ __align__(16) char smem[36864];
    ushort (*Al)[72] = (ushort(*)[72])smem;
    ushort (*Bl)[72] = (ushort(*)[72])(smem + 18432);
    float (*Ol)[132] = (float(*)[132])smem;   // overlays Al (epilogue only)

    int bid = blockIdx.x;
    int cpx = nwg >> 3;
    int swz = (bid & 7) * cpx + (bid >> 3);
    int n0 = (swz % nx) * 128;
    int m0 = (swz / nx) * 128;

    int tid = threadIdx.x;
    int w = tid >> 6, lane = tid & 63;
    int wm = (w >> 1) * 64, wn = (w & 1) * 64;
    int col = lane & 15, kq = lane >> 4;

    float4v acc[4][4];
    #pragma unroll
    for (int i = 0; i < 4; ++i)
        #pragma unroll
        for (int j = 0; j < 4; ++j) acc[i][j] = (float4v){0.f, 0.f, 0.f, 0.f};

    int kTiles = Kd >> 6;
    for (int kt = 0; kt < kTiles; ++kt) {
        __syncthreads();
        #pragma unroll
        for (int it = 0; it < 4; ++it) {
            int q = tid + it * 256;
            int row = q >> 3, part = q & 7;
            short8v v = *(const short8v*)(A + (size_t)(m0 + row) * Kd + (kt << 6) + part * 8);
            *(short8v*)&Al[row][part * 8] = v;
        }
        #pragma unroll
        for (int it = 0; it < 4; ++it) {
            int q = tid + it * 256;
            int row = q >> 3, part = q & 7;
            short8v v = {};
            if (EPM != 2 || n0 + row < N)
                v = *(const short8v*)(W + (size_t)(n0 + row) * Kd + (kt << 6) + part * 8);
            *(short8v*)&Bl[row][part * 8] = v;
        }
        __syncthreads();
        #pragma unroll
        for (int ksub = 0; ksub < 2; ++ksub) {
            short8v af[4], bf[4];
            #pragma unroll
            for (int mf = 0; mf < 4; ++mf)
                af[mf] = *(const short8v*)&Al[wm + mf * 16 + col][ksub * 32 + kq * 8];
            #pragma unroll
            for (int nf = 0; nf < 4; ++nf)
                bf[nf] = *(const short8v*)&Bl[wn + nf * 16 + col][ksub * 32 + kq * 8];
            #pragma unroll
            for (int mf = 0; mf < 4; ++mf)
                #pragma unroll
                for (int nf = 0; nf < 4; ++nf)
                    acc[mf][nf] = __builtin_amdgcn_mfma_f32_16x16x32_bf16(
                        af[mf], bf[nf], acc[mf][nf], 0, 0, 0);
        }
    }

    // Epilogue: 4 rounds of 32-n strips through Ol (overlaying Al)
    int b = m0 >> 7;
    #pragma unroll
    for (int q = 0; q < 4; ++q) {
        __syncthreads();
        #pragma unroll
        for (int nf = 0; nf < 4; ++nf) {
            int gnl = wn + nf * 16;
            if ((gnl >> 5) != q) continue;
            int gn = n0 + gnl + col;
            float bn = (EPM == 2 && gn >= N) ? 0.f : bias[gn];
            int nl = gnl - q * 32 + col;
            #pragma unroll
            for (int mf = 0; mf < 4; ++mf) {
                #pragma unroll
                for (int r = 0; r < 4; ++r) {
                    float v = acc[mf][nf][r] + bn;
                    if (EPM == 1) v = 0.5f * v * (1.f + erff(v * 0.70710678118654752f));
                    Ol[nl][wm + mf * 16 + kq * 4 + r] = v;
                }
            }
        }
        __syncthreads();
        int nloc = tid >> 3, c0 = (tid & 7) * 16;
        int gn = n0 + q * 32 + nloc;
        if (EPM == 2 && gn >= N) continue;
        float* zr = Z + ((size_t)b * LDO + gn) * CC + c0;
        #pragma unroll
        for (int i = 0; i < 4; ++i) {
            float4 v = *(float4*)&Ol[nloc][c0 + i * 4];
            if (EPM == 1) {
                float4 o = *(float4*)(zr + i * 4);
                v.x += o.x; v.y += o.y; v.z += o.z; v.w += o.w;
                *(float4*)(zr + i * 4) = v;
            } else {
                int mb = m0 + c0 + i * 4;
                float4 s4 = *(const float4*)(epS + mb);
                float4 m4 = *(const float4*)(epM + mb);
                v.x = v.x * s4.x + m4.x; v.y = v.y * s4.y + m4.y;
                v.z = v.z * s4.z + m4.z; v.w = v.w * s4.w + m4.w;
                *(float4*)(zr + i * 4) = v;
            }
        }
    }
}

// W [K][N] f32 -> WT [N][K] bf16  (block (32,8), grid (K/32, ceil(N/32)))
__global__ void wtrans_kernel(const float* __restrict__ W, ushort* __restrict__ WT,
                              int Kd, int N) {
    __shared__ float t[32][33];
    int k0 = blockIdx.x * 32, n0 = blockIdx.y * 32;
    int tx = threadIdx.x, ty = threadIdx.y;
    for (int i = ty; i < 32; i += 8) {
        int n = n0 + tx;
        t[i][tx] = (n < N) ? W[(size_t)(k0 + i) * N + n] : 0.f;
    }
    __syncthreads();
    for (int i = ty; i < 32; i += 8) {
        int n = n0 + i;
        if (n < N) WT[(size_t)n * Kd + k0 + tx] = f2bf(t[tx][i]);
    }
}

// ---------------------------------------------------------------------------
// normalize cluster embeds rows, write transposed cnT[h][k]
// ---------------------------------------------------------------------------
__global__ void cn_norm_kernel(const float* __restrict__ ce, float* __restrict__ cnT) {
    int k = blockIdx.x, h = threadIdx.x;
    float v = ce[(size_t)k * HH + h];
    __shared__ float sh[128];
    sh[h] = v * v;
    __syncthreads();
    for (int o = 64; o >= 1; o >>= 1) {
        if (h < o) sh[h] += sh[h + o];
        __syncthreads();
    }
    float nrm = sqrtf(sh[0]) + 1e-8f;
    cnT[(size_t)h * KK + k] = v / nrm;
}

// per-token 1/(||h||+1e-8)
__global__ void rownorm_kernel(const float* __restrict__ h, float* __restrict__ rn) {
    size_t row = (size_t)blockIdx.x * 256 + threadIdx.x;
    const float4* hp = (const float4*)(h + row * HH);
    float s = 0.f;
    #pragma unroll
    for (int i = 0; i < 32; ++i) {
        float4 v = hp[i];
        s += v.x * v.x + v.y * v.y + v.z * v.z + v.w * v.w;
    }
    rn[row] = 1.f / (sqrtf(s) + 1e-8f);
}

// Qp[k,h'] = (sum_h wk_w[h',h] * Q[k,h]) / sqrt(H);  qb[k] = (Q[k].wk_b)/sqrt(H)
__global__ void qprime_kernel(const float* __restrict__ Q, const float* __restrict__ wk_w,
                              const float* __restrict__ wk_b, float* __restrict__ Qp,
                              float* __restrict__ qb) {
    int k = blockIdx.x;
    int hp = threadIdx.x;
    __shared__ float qrow[128];
    __shared__ float red[128];
    qrow[hp] = Q[(size_t)k * HH + hp];
    __syncthreads();
    float s = 0.f;
    for (int h = 0; h < HH; ++h) s = fmaf(qrow[h], wk_w[(size_t)hp * HH + h], s);
    const float rs = 0.088388347648318447f;
    Qp[(size_t)k * HH + hp] = s * rs;
    red[hp] = qrow[hp] * wk_b[hp];
    __syncthreads();
    for (int o = 64; o >= 1; o >>= 1) {
        if (hp < o) red[hp] += red[hp + o];
        __syncthreads();
    }
    if (hp == 0) qb[k] = red[0] * rs;
}

// ---------------------------------------------------------------------------
// softmax over K=64, Bernoulli mask (u8, [B,K,L]), p-mean partials
// ---------------------------------------------------------------------------
__global__ __launch_bounds__(256)
void pmask_kernel(const float* __restrict__ sp, const float* __restrict__ rn,
                  const float* __restrict__ bern, unsigned char* __restrict__ Mt,
                  float* __restrict__ ppart) {
    int b = blockIdx.y;
    int l0 = blockIdx.x * 32;
    int tid = threadIdx.x;
    int wv = tid >> 6, lane = tid & 63;
    __shared__ float Msh[64][33];
    __shared__ float psum[4][64];
    float pa = 0.f;
    for (int tt = 0; tt < 8; ++tt) {
        int l = l0 + wv * 8 + tt;
        size_t tok = (size_t)b * LL + l;
        float s = sp[tok * 64 + lane] * rn[tok];
        float mx = s;
        #pragma unroll
        for (int o = 32; o >= 1; o >>= 1) mx = fmaxf(mx, __shfl_xor(mx, o));
        float ev = expf(s - mx);
        float sm = ev;
        #pragma unroll
        for (int o = 32; o >= 1; o >>= 1) sm += __shfl_xor(sm, o);
        float p = ev / sm;
        pa += p;
        Msh[lane][wv * 8 + tt] = (bern[tok * KK + lane] < p) ? 1.f : 0.f;
    }
    psum[wv][lane] = pa;
    __syncthreads();
    for (int q = tid; q < 64 * 32; q += 256) {
        int k = q >> 5, j = q & 31;
        Mt[((size_t)b * KK + k) * LL + l0 + j] = (unsigned char)Msh[k][j];
    }
    if (tid < 64)
        ppart[((size_t)b * (LL / 32) + blockIdx.x) * KK + tid] =
            psum[0][tid] + psum[1][tid] + psum[2][tid] + psum[3][tid];
}

__global__ void pmean_final_kernel(const float* __restrict__ part, float* __restrict__ pm) {
    int b = blockIdx.x, k = threadIdx.x;
    float s = 0.f;
    for (int i = 0; i < LL / 32; ++i) s += part[((size_t)b * (LL / 32) + i) * KK + k];
    pm[b * KK + k] = s * (1.f / LL);
}

// ---------------------------------------------------------------------------
// scores[b,k,l] = Qp[k,:].h[b,l,:] + qb[k]
// ---------------------------------------------------------------------------
__global__ __launch_bounds__(256)
void scores_kernel(const float* __restrict__ Qp, const float* __restrict__ hmat,
                   const float* __restrict__ qb, float* __restrict__ S) {
    __shared__ float QT[128][64];
    __shared__ float KT[32][128];
    int tid = threadIdx.x;
    int b = blockIdx.y;
    int l0 = blockIdx.x * 128;
    for (int q = tid; q < 64 * 128; q += 256) {
        int k = q >> 7, h = q & 127;
        QT[h][k] = Qp[q];
    }
    int tx = tid & 15, ty = tid >> 4;
    float acc[4][8] = {};
    const float* Kb = hmat + (size_t)b * LL * HH;
    for (int ht = 0; ht < HH; ht += 32) {
        __syncthreads();
        #pragma unroll
        for (int it = 0; it < 4; ++it) {
            int q = tid + it * 256;
            int row = q >> 3;
            int hq = (q & 7) << 2;
            float4 v = *(const float4*)(Kb + (size_t)(l0 + row) * HH + ht + hq);
            KT[hq][row] = v.x; KT[hq + 1][row] = v.y;
            KT[hq + 2][row] = v.z; KT[hq + 3][row] = v.w;
        }
        __syncthreads();
        #pragma unroll
        for (int h = 0; h < 32; ++h) {
            float qv[4], kv[8];
            *(float4*)&qv[0] = *(const float4*)&QT[ht + h][ty * 4];
            *(float4*)&kv[0] = *(const float4*)&KT[h][tx * 4];
            *(float4*)&kv[4] = *(const float4*)&KT[h][64 + tx * 4];
            #pragma unroll
            for (int i = 0; i < 4; ++i)
                #pragma unroll
                for (int j = 0; j < 8; ++j)
                    acc[i][j] = fmaf(qv[i], kv[j], acc[i][j]);
        }
    }
    #pragma unroll
    for (int i = 0; i < 4; ++i) {
        int k = ty * 4 + i;
        float bq = qb[k];
        #pragma unroll
        for (int jj = 0; jj < 8; jj += 4) {
            int l = l0 + (jj ? 64 + tx * 4 : tx * 4);
            float o[4];
            #pragma unroll
            for (int j = 0; j < 4; ++j) o[j] = acc[i][jj + j] + bq;
            *(float4*)(S + ((size_t)b * KK + k) * LL + l) = *(float4*)o;
        }
    }
}

// ---------------------------------------------------------------------------
// aw = softmax_l( exp(scores) * Mt ), in place on S
// ---------------------------------------------------------------------------
__global__ __launch_bounds__(256)
void aw_kernel(float* __restrict__ S, const unsigned char* __restrict__ Mt) {
    size_t base = (size_t)blockIdx.x * LL;
    int tid = threadIdx.x;
    float t[8];
    float mx = -1e30f;
    #pragma unroll
    for (int i = 0; i < 8; ++i) {
        int l = tid + i * 256;
        float v = expf(S[base + l]) * (float)Mt[base + l];
        t[i] = v;
        mx = fmaxf(mx, v);
    }
    __shared__ float shA[4];
    __shared__ float shB[4];
    #pragma unroll
    for (int o = 32; o >= 1; o >>= 1) mx = fmaxf(mx, __shfl_xor(mx, o));
    if ((tid & 63) == 0) shA[tid >> 6] = mx;
    __syncthreads();
    mx = fmaxf(fmaxf(shA[0], shA[1]), fmaxf(shA[2], shA[3]));
    float e[8];
    float sum = 0.f;
    #pragma unroll
    for (int i = 0; i < 8; ++i) { e[i] = expf(t[i] - mx); sum += e[i]; }
    #pragma unroll
    for (int o = 32; o >= 1; o >>= 1) sum += __shfl_xor(sum, o);
    if ((tid & 63) == 0) shB[tid >> 6] = sum;
    __syncthreads();
    sum = (shB[0] + shB[1]) + (shB[2] + shB[3]);
    float inv = 1.f / sum;
    #pragma unroll
    for (int i = 0; i < 8; ++i) S[base + tid + i * 256] = e[i] * inv;
}

// ---------------------------------------------------------------------------
// awh split-L partials
// ---------------------------------------------------------------------------
__global__ __launch_bounds__(256)
void awh_part_kernel(const float* __restrict__ AWs, const float* __restrict__ hmat,
                     float* __restrict__ part) {
    __shared__ float AT[32][64];
    __shared__ float VT[32][128];
    int b = blockIdx.y, sp = blockIdx.x;
    int tid = threadIdx.x;
    int tx = tid & 15, ty = tid >> 4;
    float acc[4][8] = {};
    const float* Ab = AWs + (size_t)b * KK * LL + sp * 512;
    const float* Vb = hmat + ((size_t)b * LL + sp * 512) * HH;
    for (int lt = 0; lt < 512; lt += 32) {
        __syncthreads();
        #pragma unroll
        for (int it = 0; it < 2; ++it) {
            int q = tid + it * 256;
            int row = q >> 3;
            int lq = (q & 7) << 2;
            float4 v = *(const float4*)(Ab + (size_t)row * LL + lt + lq);
            AT[lq][row] = v.x; AT[lq + 1][row] = v.y;
            AT[lq + 2][row] = v.z; AT[lq + 3][row] = v.w;
        }
        #pragma unroll
        for (int it = 0; it < 4; ++it) {
            int q = tid + it * 256;
            int lr = q >> 5;
            int hc = (q & 31) << 2;
            *(float4*)&VT[lr][hc] = *(const float4*)(Vb + (size_t)(lt + lr) * HH + hc);
        }
        __syncthreads();
        #pragma unroll
        for (int l = 0; l < 32; ++l) {
            float av[4], vv[8];
            *(float4*)&av[0] = *(const float4*)&AT[l][ty * 4];
            *(float4*)&vv[0] = *(const float4*)&VT[l][tx * 4];
            *(float4*)&vv[4] = *(const float4*)&VT[l][64 + tx * 4];
            #pragma unroll
            for (int i = 0; i < 4; ++i)
                #pragma unroll
                for (int j = 0; j < 8; ++j)
                    acc[i][j] = fmaf(av[i], vv[j], acc[i][j]);
        }
    }
    #pragma unroll
    for (int i = 0; i < 4; ++i) {
        int k = ty * 4 + i;
        #pragma unroll
        for (int jj = 0; jj < 8; jj += 4) {
            int h = (jj ? 64 + tx * 4 : tx * 4);
            float o[4];
            #pragma unroll
            for (int j = 0; j < 4; ++j) o[j] = acc[i][jj + j];
            *(float4*)(part + (((size_t)b * 4 + sp) * KK + k) * HH + h) = *(float4*)o;
        }
    }
}

__global__ void awh_reduce_kernel(const float* __restrict__ part, float* __restrict__ awh) {
    int bk = blockIdx.x, h = threadIdx.x;
    int b = bk >> 6, k = bk & 63;
    float s = 0.f;
    #pragma unroll
    for (int sp = 0; sp < 4; ++sp)
        s += part[(((size_t)b * 4 + sp) * KK + k) * HH + h];
    awh[(size_t)bk * HH + h] = s;
}

__global__ void newce_kernel(const float* __restrict__ ao, const float* __restrict__ pm,
                             float* __restrict__ outTail) {
    int k = blockIdx.x, h = threadIdx.x;
    float s = 0.f;
    for (int b = 0; b < BB; ++b)
        s += ao[((size_t)b * KK + k) * HH + h] * pm[b * KK + k];
    outTail[(size_t)k * HH + h] = s * (1.f / BB);
}

// z = (z - mean2)*rstd2 in place; grid (32, B), block 256
__global__ void revin_apply_kernel(float* __restrict__ z,
                                   const float* __restrict__ mu, const float* __restrict__ rs) {
    int b = blockIdx.y;
    size_t base = (size_t)b * LL * CC + (size_t)blockIdx.x * 8192;
    int c0 = (threadIdx.x * 4) & 127;
    float4 m4 = *(const float4*)(mu + b * CC + c0);
    float4 r4 = *(const float4*)(rs + b * CC + c0);
    #pragma unroll
    for (int j = 0; j < 8; ++j) {
        float4 v = *(float4*)(z + base + threadIdx.x * 4 + j * 1024);
        v.x = (v.x - m4.x) * r4.x; v.y = (v.y - m4.y) * r4.y;
        v.z = (v.z - m4.z) * r4.z; v.w = (v.w - m4.w) * r4.w;
        *(float4*)(z + base + threadIdx.x * 4 + j * 1024) = v;
    }
}

// timestep BN stats: per l over (b, c)
__global__ __launch_bounds__(256)
void bnt_stats_kernel(const float* __restrict__ z, float* __restrict__ mu,
                      float* __restrict__ rv) {
    int l = blockIdx.x;
    int tid = threadIdx.x;
    float s = 0.f, s2 = 0.f;
    for (int i = tid; i < BB * CC; i += 256) {
        int b = i >> 7, c = i & 127;
        float v = z[((size_t)b * LL + l) * CC + c];
        s += v; s2 += v * v;
    }
    #pragma unroll
    for (int o = 32; o >= 1; o >>= 1) { s += __shfl_xor(s, o); s2 += __shfl_xor(s2, o); }
    __shared__ float shA[4];
    __shared__ float shB[4];
    if ((tid & 63) == 0) { shA[tid >> 6] = s; shB[tid >> 6] = s2; }
    __syncthreads();
    if (tid == 0) {
        float ts = (shA[0] + shA[1]) + (shA[2] + shA[3]);
        float tq = (shB[0] + shB[1]) + (shB[2] + shB[3]);
        float m = ts / (float)(BB * CC);
        float var = tq / (float)(BB * CC) - m * m;
        var = fmaxf(var, 0.f);
        mu[l] = m;
        rv[l] = 1.f / sqrtf(var + EPSf);
    }
}

// [B,L,C] f32 -> [B,C,L] bf16, optional timestep-BN on the fly
template <bool DO_BN>
__global__ void transpose_bn_kernel(const float* __restrict__ in, ushort* __restrict__ out,
                                    const float* __restrict__ mu, const float* __restrict__ rv,
                                    const float* __restrict__ g, const float* __restrict__ be) {
    __shared__ float tile[32][33];
    int l0 = blockIdx.x * 32, c0 = blockIdx.y * 32, b = blockIdx.z;
    int tx = threadIdx.x, ty = threadIdx.y;
    const float* ib = in + (size_t)b * LL * CC;
    for (int i = ty; i < 32; i += 8) {
        int l = l0 + i;
        float v = ib[(size_t)l * CC + c0 + tx];
        if (DO_BN) v = (v - mu[l]) * rv[l] * g[l] + be[l];
        tile[i][tx] = v;
    }
    __syncthreads();
    ushort* ob = out + (size_t)b * CC * LL;
    for (int i = ty; i < 32; i += 8)
        ob[(size_t)(c0 + i) * LL + l0 + tx] = f2bf(tile[tx][i]);
}

// feature BN partial stats
__global__ void bnf_part_kernel(const float* __restrict__ z, float* __restrict__ part) {
    int c = threadIdx.x;
    const int rows = (BB * LL) / 1024;
    size_t r0 = (size_t)blockIdx.x * rows;
    float s = 0.f, s2 = 0.f;
    for (int r = 0; r < rows; ++r) {
        float v = z[(r0 + r) * CC + c];
        s += v; s2 += v * v;
    }
    part[(size_t)blockIdx.x * 256 + c] = s;
    part[(size_t)blockIdx.x * 256 + 128 + c] = s2;
}

__global__ void bnf_final_kernel(const float* __restrict__ part, const float* __restrict__ g,
                                 const float* __restrict__ be, float* __restrict__ mu,
                                 float* __restrict__ sA, float* __restrict__ tA) {
    int c = threadIdx.x;
    float s = 0.f, s2 = 0.f;
    for (int i = 0; i < 1024; ++i) {
        s += part[(size_t)i * 256 + c];
        s2 += part[(size_t)i * 256 + 128 + c];
    }
    float m = s / (float)(BB * LL);
    float var = s2 / (float)(BB * LL) - m * m;
    var = fmaxf(var, 0.f);
    float rvv = 1.f / sqrtf(var + EPSf);
    mu[c] = m;
    sA[c] = rvv * g[c];
    tA[c] = be[c];
}

// ---------------------------------------------------------------------------
extern "C" void kernel_launch(void* const* d_in, const int* in_sizes, int n_in,
                              void* d_out, int out_size, void* d_ws, size_t ws_size,
                              hipStream_t stream) {
    const float* x     = (const float*)d_in[0];
    const float* bern  = (const float*)d_in[1];
    const float* ce    = (const float*)d_in[2];
    const float* wq_w  = (const float*)d_in[3];
    const float* wq_b  = (const float*)d_in[4];
    const float* wk_w  = (const float*)d_in[5];
    const float* wk_b  = (const float*)d_in[6];
    const float* wv_w  = (const float*)d_in[7];
    const float* wv_b  = (const float*)d_in[8];
    const float* cm_w1 = (const float*)d_in[9];
    const float* cm_b1 = (const float*)d_in[10];
    const float* cm_w2 = (const float*)d_in[11];
    const float* cm_b2 = (const float*)d_in[12];
    const float* tm_w1 = (const float*)d_in[13];
    const float* tm_b1 = (const float*)d_in[14];
    const float* tm_w2 = (const float*)d_in[15];
    const float* tm_b2 = (const float*)d_in[16];
    const float* bn_t_g = (const float*)d_in[17];
    const float* bn_t_b = (const float*)d_in[18];
    const float* lin_t_w = (const float*)d_in[19];
    const float* lin_t_b = (const float*)d_in[20];
    const float* bn_f_g = (const float*)d_in[21];
    const float* bn_f_b = (const float*)d_in[22];
    const float* f1_w  = (const float*)d_in[23];
    const float* f1_b  = (const float*)d_in[24];
    const float* f2_w  = (const float*)d_in[25];
    const float* f2_b  = (const float*)d_in[26];
    const float* out_w = (const float*)d_in[27];
    const float* out_b = (const float*)d_in[28];
    (void)in_sizes; (void)n_in; (void)out_size;

    float* y = (float*)d_out;                         // [B,P,C]
    float* ceOut = y + (size_t)BB * PP * CC;          // [K,H]

    float* ws = (float*)d_ws;
    size_t off = 0;
    auto alloc = [&](size_t n) { float* p = ws + off; off += n; return p; };
    float* mean1  = alloc(BB * CC);
    float* rstd1  = alloc(BB * CC);
    float* std1   = alloc(BB * CC);
    float* mean2  = alloc(BB * CC);
    float* rstd2  = alloc(BB * CC);
    float* std2   = alloc(BB * CC);
    float* bnmu   = alloc(LL);
    float* bnrv   = alloc(LL);
    float* bfpart = alloc(1024 * 256);
    float* bfmu   = alloc(CC);
    float* bfs    = alloc(CC);
    float* bft    = alloc(CC);
    float* qbuf   = alloc(KK * HH);
    float* qp     = alloc(KK * HH);
    float* qb     = alloc(KK);
    float* cnT    = alloc(HH * KK);
    float* rn     = alloc((size_t)BB * LL);
    float* ppart  = alloc((size_t)BB * (LL / 32) * KK);
    float* pmean  = alloc(BB * KK);
    float* awhprt = alloc((size_t)BB * 4 * KK * HH);
    float* awh    = alloc((size_t)BB * KK * HH);
    float* aobuf  = alloc((size_t)BB * KK * HH);
    ushort* wsp   = (ushort*)alloc(7 * 2 * 16384 / 2);        // 7 split 128x128 weights
    ushort* wtT   = (ushort*)alloc((size_t)LL * LL / 2);      // lin_t_w^T bf16
    ushort* owT   = (ushort*)alloc((size_t)PP * LL / 2 + 64); // out_w^T bf16
    float* S      = alloc((size_t)BB * KK * LL);
    float* buf0   = alloc((size_t)BB * LL * CC);
    float* buf2   = alloc((size_t)BB * LL * CC);
    unsigned char* Mt = (unsigned char*)(ws + off);           // [B,K,L] u8
    ushort* abf = (ushort*)S;   // bf16 [B,C,L] overlay on S (dead by mixer time)
    (void)ws_size;

    auto whi = [&](int i) { return wsp + (size_t)i * 2 * 16384; };
    auto wlo = [&](int i) { return wsp + (size_t)i * 2 * 16384 + 16384; };

    const int ML = BB * LL;      // 131072
    dim3 tb(32, 8);
    dim3 tgrid(LL / 32, CC / 32, BB);
    dim3 wsg(4, 4);

    // 0) weight prep
    wtrans_kernel<<<dim3(LL / 32, LL / 32), tb, 0, stream>>>(lin_t_w, wtT, LL, LL);
    wtrans_kernel<<<dim3(LL / 32, (PP + 31) / 32), tb, 0, stream>>>(out_w, owT, LL, PP);
    wsplit_kernel<<<wsg, tb, 0, stream>>>(cm_w1, whi(0), wlo(0));
    wsplit_kernel<<<wsg, tb, 0, stream>>>(cm_w2, whi(1), wlo(1));
    wsplit_kernel<<<wsg, tb, 0, stream>>>(tm_w1, whi(2), wlo(2));
    wsplit_kernel<<<wsg, tb, 0, stream>>>(tm_w2, whi(3), wlo(3));
    wsplit_kernel<<<wsg, tb, 0, stream>>>(f1_w, whi(4), wlo(4));
    wsplit_kernel<<<wsg, tb, 0, stream>>>(f2_w, whi(5), wlo(5));
    wsplit_kernel<<<wsg, tb, 0, stream>>>(wv_w, whi(6), wlo(6));

    // 1) RevIN-1 stats
    colstats_kernel<<<dim3(BB), dim3(128, 8), 0, stream>>>(x, mean1, rstd1, std1);
    // 2) buf0 = relu(norm(x) @ cm_w1 + cm_b1)
    mfma_sq_kernel<1, 1, 0><<<dim3(ML / 128), 256, 0, stream>>>(
        x, whi(0), wlo(0), cm_b1, buf0, mean1, rstd1, nullptr, CC);
    // 3) h = buf2
    mfma_sq_kernel<0, 0, 0><<<dim3(ML / 128), 256, 0, stream>>>(
        buf0, whi(1), wlo(1), cm_b2, buf2, nullptr, nullptr, nullptr, 0);
    // 4) Q, Qp, qb
    gemm_kernel<<<dim3(1, 1), 256, 0, stream>>>(ce, wq_w, wq_b, qbuf,
        KK, HH, HH, HH, HH, HH);
    qprime_kernel<<<dim3(KK), dim3(128), 0, stream>>>(qbuf, wk_w, wk_b, qp, qb);
    // 5) normalized codebook
    cn_norm_kernel<<<dim3(KK), dim3(128), 0, stream>>>(ce, cnT);
    // 6) token norms
    rownorm_kernel<<<dim3(ML / 256), 256, 0, stream>>>(buf2, rn);
    // 7) routing scores
    gemm_kernel<<<dim3(1, ML / 128), 256, 0, stream>>>(buf2, cnT, nullptr, S,
        ML, KK, HH, HH, KK, KK);
    // 8) softmax/mask/p-mean
    pmask_kernel<<<dim3(LL / 32, BB), 256, 0, stream>>>(S, rn, bern, Mt, ppart);
    pmean_final_kernel<<<dim3(BB), dim3(64), 0, stream>>>(ppart, pmean);
    // 9) attn scores
    scores_kernel<<<dim3(LL / 128, BB), 256, 0, stream>>>(qp, buf2, qb, S);
    // 10) masked double-exp softmax
    aw_kernel<<<dim3(BB * KK), 256, 0, stream>>>(S, Mt);
    // 11) awh -> ao -> cluster update
    awh_part_kernel<<<dim3(4, BB), 256, 0, stream>>>(S, buf2, awhprt);
    awh_reduce_kernel<<<dim3(BB * KK), dim3(128), 0, stream>>>(awhprt, awh);
    mfma_sq_kernel<0, 0, 0><<<dim3((BB * KK) / 128), 256, 0, stream>>>(
        awh, whi(6), wlo(6), wv_b, aobuf, nullptr, nullptr, nullptr, 0);
    newce_kernel<<<dim3(KK), dim3(128), 0, stream>>>(aobuf, pmean, ceOut);
    // 12) temporal module
    mfma_sq_kernel<0, 1, 0><<<dim3(ML / 128), 256, 0, stream>>>(
        buf2, whi(2), wlo(2), tm_b1, buf0, nullptr, nullptr, nullptr, 0);
    mfma_sq_kernel<0, 0, 0><<<dim3(ML / 128), 256, 0, stream>>>(
        buf0, whi(3), wlo(3), tm_b2, buf2, nullptr, nullptr, nullptr, 0);
    // 13) RevIN-2 stats + apply (z in buf2)
    colstats_kernel<<<dim3(BB), dim3(128, 8), 0, stream>>>(buf2, mean2, rstd2, std2);
    revin_apply_kernel<<<dim3(32, BB), 256, 0, stream>>>(buf2, mean2, rstd2);
    // 14) 4 mixer blocks
    for (int blkI = 0; blkI < 4; ++blkI) {
        bnt_stats_kernel<<<dim3(LL), 256, 0, stream>>>(buf2, bnmu, bnrv);
        transpose_bn_kernel<true><<<tgrid, tb, 0, stream>>>(buf2, abf, bnmu, bnrv, bn_t_g, bn_t_b);
        mfma_gemm_kernel<1><<<dim3(1024), 256, 0, stream>>>(
            abf, wtT, lin_t_b, buf2, LL, LL, LL, 16, 1024, nullptr, nullptr);
        bnf_part_kernel<<<dim3(1024), dim3(128), 0, stream>>>(buf2, bfpart);
        bnf_final_kernel<<<dim3(1), dim3(128), 0, stream>>>(bfpart, bn_f_g, bn_f_b, bfmu, bfs, bft);
        mfma_sq_kernel<2, 2, 0><<<dim3(ML / 128), 256, 0, stream>>>(
            buf2, whi(4), wlo(4), f1_b, buf0, bfmu, bfs, bft, 0);
        mfma_sq_kernel<0, 0, 1><<<dim3(ML / 128), 256, 0, stream>>>(
            buf0, whi(5), wlo(5), f2_b, buf2, nullptr, nullptr, nullptr, 0);
    }
    // 15) head via MFMA: y[b,p,c] = (z^T @ out_w + out_b) * std2 + mean2
    transpose_bn_kernel<false><<<tgrid, tb, 0, stream>>>(buf2, abf,
        nullptr, nullptr, nullptr, nullptr);
    mfma_gemm_kernel<2><<<dim3(192), 256, 0, stream>>>(
        abf, owT, out_b, y, PP, LL, PP, 3, 192, std2, mean2);
}